// Round 4
// baseline (20972.035 us; speedup 1.0000x reference)
//
#include <hip/hip_runtime.h>
#include <math.h>

// Sizes fixed by the problem
#define D_DIM 1024
#define S_LEN 2048
#define B_SZ  4
#define GRU_BLOCKS 256   // x 512 threads (8 waves): 4 L1-waves + 4 L2-waves

union F4 { float4 v; float f[4]; };

__device__ __forceinline__ float gelu_f(float x) {
  return 0.5f * x * (1.0f + erff(x * 0.70710678118654752440f));
}
__device__ __forceinline__ float sigmoid_f(float x) {
  return __fdividef(1.0f, 1.0f + __expf(-x));
}
// fast tanh via exp: clamp keeps e^{2x} finite; |err| ~1e-7 rel.
__device__ __forceinline__ float tanh_f(float x) {
  const float xc = fminf(fmaxf(x, -15.0f), 15.0f);
  const float a = __expf(2.0f * xc);
  return __fdividef(a - 1.0f, a + 1.0f);
}

// ---------------- LayerNorm: one block per row of 1024 ----------------
__global__ __launch_bounds__(256) void ln_kernel(
    const float* __restrict__ x, const float* __restrict__ gamma,
    const float* __restrict__ beta, float* __restrict__ out) {
  const int row = blockIdx.x;
  const int tid = threadIdx.x;
  const int wave = tid >> 6, lane = tid & 63;
  const float4 v = ((const float4*)(x + (size_t)row * D_DIM))[tid];
  float s  = v.x + v.y + v.z + v.w;
  float ss = v.x * v.x + v.y * v.y + v.z * v.z + v.w * v.w;
#pragma unroll
  for (int m = 1; m < 64; m <<= 1) {
    s  += __shfl_xor(s,  m, 64);
    ss += __shfl_xor(ss, m, 64);
  }
  __shared__ float r0[4], r1[4];
  if (lane == 0) { r0[wave] = s; r1[wave] = ss; }
  __syncthreads();
  s  = r0[0] + r0[1] + r0[2] + r0[3];
  ss = r1[0] + r1[1] + r1[2] + r1[3];
  const float mean = s * (1.0f / D_DIM);
  const float var  = ss * (1.0f / D_DIM) - mean * mean;
  const float inv  = rsqrtf(var + 1e-5f);
  const float4 g4 = ((const float4*)gamma)[tid];
  const float4 b4 = ((const float4*)beta)[tid];
  float4 o;
  o.x = (v.x - mean) * inv * g4.x + b4.x;
  o.y = (v.y - mean) * inv * g4.y + b4.y;
  o.z = (v.z - mean) * inv * g4.z + b4.z;
  o.w = (v.w - mean) * inv * g4.w + b4.w;
  ((float4*)(out + (size_t)row * D_DIM))[tid] = o;
}

// ---------------- Generic SGEMM: C = A @ W^T (+bias)(+act)(+res) ----------------
#define BM 128
#define BN 128
#define BKK 8
#define TM 8
#define TN 8
__global__ __launch_bounds__(256) void gemm_kernel(
    const float* __restrict__ A, int lda,
    const float* __restrict__ W, int ldw,
    const float* __restrict__ bias,
    const float* __restrict__ res,
    float* __restrict__ C,
    int M, int N, int K, int act) {
  __shared__ float As[BKK][BM];
  __shared__ float Bs[BKK][BN];
  const int tid = threadIdx.x;
  const int bm = blockIdx.y * BM;
  const int bn = blockIdx.x * BN;
  const int tx = tid & 15;
  const int ty = tid >> 4;
  const int lrow = tid >> 1;
  const int lk = (tid & 1) * 4;
  const float* Ag = A + (size_t)(bm + lrow) * lda + lk;
  const float* Wg = W + (size_t)(bn + lrow) * ldw + lk;

  float acc[TM][TN];
#pragma unroll
  for (int i = 0; i < TM; ++i)
#pragma unroll
    for (int j = 0; j < TN; ++j) acc[i][j] = 0.0f;

  for (int k0 = 0; k0 < K; k0 += BKK) {
    const float4 av = *(const float4*)(Ag + k0);
    const float4 wv = *(const float4*)(Wg + k0);
    __syncthreads();
    As[lk + 0][lrow] = av.x; As[lk + 1][lrow] = av.y;
    As[lk + 2][lrow] = av.z; As[lk + 3][lrow] = av.w;
    Bs[lk + 0][lrow] = wv.x; Bs[lk + 1][lrow] = wv.y;
    Bs[lk + 2][lrow] = wv.z; Bs[lk + 3][lrow] = wv.w;
    __syncthreads();
#pragma unroll
    for (int k = 0; k < BKK; ++k) {
      F4 a0, a1, b0, b1;
      a0.v = *(const float4*)(&As[k][ty * TM]);
      a1.v = *(const float4*)(&As[k][ty * TM + 4]);
      b0.v = *(const float4*)(&Bs[k][tx * TN]);
      b1.v = *(const float4*)(&Bs[k][tx * TN + 4]);
      float a[TM] = {a0.f[0], a0.f[1], a0.f[2], a0.f[3],
                     a1.f[0], a1.f[1], a1.f[2], a1.f[3]};
      float b[TN] = {b0.f[0], b0.f[1], b0.f[2], b0.f[3],
                     b1.f[0], b1.f[1], b1.f[2], b1.f[3]};
#pragma unroll
      for (int i = 0; i < TM; ++i)
#pragma unroll
        for (int j = 0; j < TN; ++j) acc[i][j] += a[i] * b[j];
    }
  }

  float bs_[TN];
#pragma unroll
  for (int j = 0; j < TN; ++j) bs_[j] = bias ? bias[bn + tx * TN + j] : 0.0f;
#pragma unroll
  for (int i = 0; i < TM; ++i) {
    const size_t coff = (size_t)(bm + ty * TM + i) * N + bn + tx * TN;
    float vals[TN];
#pragma unroll
    for (int j = 0; j < TN; ++j) {
      float v = acc[i][j] + bs_[j];
      if (act == 1) v = gelu_f(v);
      vals[j] = v;
    }
    if (res) {
#pragma unroll
      for (int j = 0; j < TN; ++j) vals[j] += res[coff + j];
    }
    *(float4*)(C + coff)     = make_float4(vals[0], vals[1], vals[2], vals[3]);
    *(float4*)(C + coff + 4) = make_float4(vals[4], vals[5], vals[6], vals[7]);
  }
}

// ---------------- Fused 2-layer persistent GRU, 1-step software pipeline ----
// 256 blocks x 512 threads (8 waves). Waves 0-3: layer-1, j = bid*4+wave.
// Waves 4-7: layer-2, same j. At global step s (s = 0..2048):
//   L1 computes h1[s]   from exchange h1[s-1] (+ precomputed xi[s]).
//   L2 computes h2[s-1] from exchange h1[s-1] (folded xi2 dot, Wih1 rows in
//      registers) and exchange h2[s-2].
// 2049 barrier rounds replace 2x2048, and the inter-layer Wih1 GEMM + the
// layer-1 y-stores disappear (h1 exchange buffer IS y1 transport).
// Parity audit (hX[t] stored into bufX[(t+1)&1]):
//   read h1[s-1] <- buf1[s&1];   write h1[s]   -> buf1[(s+1)&1]  (disjoint)
//   read h2[s-2] <- buf2[(s+1)&1]; write h2[s-1]-> buf2[s&1]     (disjoint)
//   WAR: overwrite of h1[s-1] happens at step s+1, after all its readers
//   arrived at barrier s. Same chain as the verified R3 protocol:
//   sc0sc1 stage -> LDS -> compute -> relaxed AGENT h-store -> __syncthreads
//   (drains vmcnt(0)) -> slot store -> gather poll -> __syncthreads.
// NO threadfence / NO acquire (round-1 lesson: wbl2/inv storm).
__global__ __launch_bounds__(512, 1) void gru2_kernel(
    const float* __restrict__ xi,    // (B,S,3H) layer-1 input GEMM (incl b_ih0)
    const float* __restrict__ Whh0,
    const float* __restrict__ bhh0,
    const float* __restrict__ Wih1,
    const float* __restrict__ bih1,
    const float* __restrict__ Whh1,
    const float* __restrict__ bhh1,
    const float* __restrict__ resid, // x
    float* __restrict__ y,           // (B,S,H): h2 + resid
    float* __restrict__ h1buf,       // 2*4096 floats, zeroed
    float* __restrict__ h2buf,       // 2*4096 floats, zeroed
    unsigned* __restrict__ slots)    // 256 slots x 16 u32 stride, zeroed
{
  const int tid = threadIdx.x;
  const int wave = tid >> 6, lane = tid & 63;
  const bool L2w = (wave >= 4);
  const int j = (blockIdx.x << 2) + (wave & 3);  // 0..1023

  __shared__ float h1_lds[4096];
  __shared__ float h2_lds[4096];

  // recurrent weights: wa[g][c][e] = W[g*1024+j][c*256 + lane*4 + e]
  float wa[3][4][4];
  {
    const float* Wa = L2w ? Whh1 : Whh0;
#pragma unroll
    for (int g = 0; g < 3; ++g) {
      const float* row = Wa + (size_t)(g * 1024 + j) * 1024;
#pragma unroll
      for (int c = 0; c < 4; ++c) {
        F4 q; q.v = *(const float4*)(row + (c << 8) + (lane << 2));
#pragma unroll
        for (int e = 0; e < 4; ++e) wa[g][c][e] = q.f[e];
      }
    }
  }
  // L2 only: input weights Wih1 (same k-ownership)
  float wb[3][4][4];
  if (L2w) {
#pragma unroll
    for (int g = 0; g < 3; ++g) {
      const float* row = Wih1 + (size_t)(g * 1024 + j) * 1024;
#pragma unroll
      for (int c = 0; c < 4; ++c) {
        F4 q; q.v = *(const float4*)(row + (c << 8) + (lane << 2));
#pragma unroll
        for (int e = 0; e < 4; ++e) wb[g][c][e] = q.f[e];
      }
    }
  }
  // biases: gates use  r=sig(xr+hr+b_r), z=sig(xz+hz+b_z),
  //         n=tanh(xn + b_in + r*(hn + b_hn))
  float b_r, b_z, b_in, b_hn;
  if (!L2w) {  // xi already contains b_ih0 (added by GEMM)
    b_r = bhh0[j]; b_z = bhh0[1024 + j]; b_in = 0.0f; b_hn = bhh0[2048 + j];
  } else {
    b_r  = bih1[j] + bhh1[j];
    b_z  = bih1[1024 + j] + bhh1[1024 + j];
    b_in = bih1[2048 + j];
    b_hn = bhh1[2048 + j];
  }

  // own-j hidden state (register, identical in all lanes of the wave)
  float hold[B_SZ] = {0.0f, 0.0f, 0.0f, 0.0f};

  // L1 xi prologue (t=0)
  float xr[B_SZ], xz[B_SZ], xn[B_SZ];
  if (!L2w) {
#pragma unroll
    for (int b = 0; b < B_SZ; ++b) {
      const float* xp = xi + ((size_t)(b * S_LEN)) * 3072 + j;
      xr[b] = xp[0]; xz[b] = xp[1024]; xn[b] = xp[2048];
    }
  }

  for (int s = 0; s <= S_LEN; ++s) {
    float* hr1 = h1buf + ((s & 1) << 12);        // h1[s-1]
    float* hw1 = h1buf + (((s + 1) & 1) << 12);  // h1[s]
    float* hr2 = h2buf + (((s + 1) & 1) << 12);  // h2[s-2]
    float* hw2 = h2buf + ((s & 1) << 12);        // h2[s-1]

    // Stage h1 (threads 0-255) and h2 (threads 256-511) into LDS.
    // Per instruction each wave covers 1KB contiguous (lane-adjacent 16B).
    {
      const int tt = tid & 255;
      const float* bsrc = (tid < 256) ? hr1 : hr2;
      const float* p0 = bsrc + (tt << 2);
      float4 r0, r1, r2, r3;
      asm volatile("global_load_dwordx4 %0, %1, off sc0 sc1" : "=v"(r0) : "v"(p0));
      asm volatile("global_load_dwordx4 %0, %1, off sc0 sc1" : "=v"(r1) : "v"(p0 + 1024));
      asm volatile("global_load_dwordx4 %0, %1, off sc0 sc1" : "=v"(r2) : "v"(p0 + 2048));
      asm volatile("global_load_dwordx4 %0, %1, off sc0 sc1" : "=v"(r3) : "v"(p0 + 3072));
      asm volatile("s_waitcnt vmcnt(0)" ::: "memory");
      __builtin_amdgcn_sched_barrier(0);
      float* dl = (tid < 256) ? h1_lds : h2_lds;
      ((float4*)dl)[tt]       = r0;
      ((float4*)dl)[tt + 256] = r1;
      ((float4*)dl)[tt + 512] = r2;
      ((float4*)dl)[tt + 768] = r3;
    }
    __syncthreads();

    float hnew[B_SZ];
    float sv = 0.0f;

    if (!L2w) {
      // ---- layer 1, t = s (garbage at s=2048; stores guarded) ----
      // prefetch next xi
      float nxr[B_SZ], nxz[B_SZ], nxn[B_SZ];
      {
        const int tn = (s + 1 < S_LEN) ? (s + 1) : (S_LEN - 1);
#pragma unroll
        for (int b = 0; b < B_SZ; ++b) {
          const float* xp = xi + ((size_t)(b * S_LEN + tn)) * 3072 + j;
          nxr[b] = xp[0]; nxz[b] = xp[1024]; nxn[b] = xp[2048];
        }
      }
      float a0[B_SZ], a1[B_SZ], a2[B_SZ];
#pragma unroll
      for (int b = 0; b < B_SZ; ++b) {
        float s0 = 0.f, s1 = 0.f, s2 = 0.f;
#pragma unroll
        for (int c = 0; c < 4; ++c) {
          F4 q; q.v = *((const float4*)(h1_lds + (b << 10) + (c << 8)) + lane);
#pragma unroll
          for (int e = 0; e < 4; ++e) {
            s0 += wa[0][c][e] * q.f[e];
            s1 += wa[1][c][e] * q.f[e];
            s2 += wa[2][c][e] * q.f[e];
          }
        }
        a0[b] = s0; a1[b] = s1; a2[b] = s2;
      }
#pragma unroll
      for (int m = 1; m < 64; m <<= 1)
#pragma unroll
        for (int b = 0; b < B_SZ; ++b) {
          a0[b] += __shfl_xor(a0[b], m, 64);
          a1[b] += __shfl_xor(a1[b], m, 64);
          a2[b] += __shfl_xor(a2[b], m, 64);
        }
#pragma unroll
      for (int b = 0; b < B_SZ; ++b) {
        const float r = sigmoid_f(xr[b] + a0[b] + b_r);
        const float z = sigmoid_f(xz[b] + a1[b] + b_z);
        const float n = tanh_f(xn[b] + r * (a2[b] + b_hn));
        hnew[b] = (1.0f - z) * n + z * hold[b];
        if (s < S_LEN) hold[b] = hnew[b];
      }
      sv = hnew[0];
      sv = (lane == 1) ? hnew[1] : sv;
      sv = (lane == 2) ? hnew[2] : sv;
      sv = (lane == 3) ? hnew[3] : sv;
      if (s < S_LEN && lane < B_SZ)
        __hip_atomic_store(hw1 + (lane << 10) + j, sv,
                           __ATOMIC_RELAXED, __HIP_MEMORY_SCOPE_AGENT);
      // rotate xi double-buffer
#pragma unroll
      for (int b = 0; b < B_SZ; ++b) {
        xr[b] = nxr[b]; xz[b] = nxz[b]; xn[b] = nxn[b];
      }
    } else {
      // ---- layer 2, t2 = s-1 (garbage at s=0; hold/stores guarded) ----
      // per batch: xiR/xiZ/xiN = wb . h1 ; hhR/hhZ/hhN = wa . h2
      float v0[B_SZ], v1[B_SZ], v2[B_SZ], v3[B_SZ];
#pragma unroll
      for (int b = 0; b < B_SZ; ++b) {
        float xiR = 0.f, xiZ = 0.f, xiN = 0.f;
        float hhR = 0.f, hhZ = 0.f, hhN = 0.f;
#pragma unroll
        for (int c = 0; c < 4; ++c) {
          F4 q1; q1.v = *((const float4*)(h1_lds + (b << 10) + (c << 8)) + lane);
          F4 q2; q2.v = *((const float4*)(h2_lds + (b << 10) + (c << 8)) + lane);
#pragma unroll
          for (int e = 0; e < 4; ++e) {
            xiR += wb[0][c][e] * q1.f[e];
            xiZ += wb[1][c][e] * q1.f[e];
            xiN += wb[2][c][e] * q1.f[e];
            hhR += wa[0][c][e] * q2.f[e];
            hhZ += wa[1][c][e] * q2.f[e];
            hhN += wa[2][c][e] * q2.f[e];
          }
        }
        v0[b] = xiR + hhR;  // r pre-activation (minus bias)
        v1[b] = xiZ + hhZ;  // z
        v2[b] = xiN;        // input-side n
        v3[b] = hhN;        // hidden-side n (gated by r)
      }
#pragma unroll
      for (int m = 1; m < 64; m <<= 1)
#pragma unroll
        for (int b = 0; b < B_SZ; ++b) {
          v0[b] += __shfl_xor(v0[b], m, 64);
          v1[b] += __shfl_xor(v1[b], m, 64);
          v2[b] += __shfl_xor(v2[b], m, 64);
          v3[b] += __shfl_xor(v3[b], m, 64);
        }
#pragma unroll
      for (int b = 0; b < B_SZ; ++b) {
        const float r = sigmoid_f(v0[b] + b_r);
        const float z = sigmoid_f(v1[b] + b_z);
        const float n = tanh_f(v2[b] + b_in + r * (v3[b] + b_hn));
        hnew[b] = (1.0f - z) * n + z * hold[b];
        if (s >= 1) hold[b] = hnew[b];
      }
      sv = hnew[0];
      sv = (lane == 1) ? hnew[1] : sv;
      sv = (lane == 2) ? hnew[2] : sv;
      sv = (lane == 3) ? hnew[3] : sv;
      if (s >= 1 && lane < B_SZ)
        __hip_atomic_store(hw2 + (lane << 10) + j, sv,
                           __ATOMIC_RELAXED, __HIP_MEMORY_SCOPE_AGENT);
    }

    // ---- device-wide barrier: slot stores + gather poll ----
    __syncthreads();  // drains vmcnt(0) per wave: all h-stores at LLC
    if (tid == 0)
      __hip_atomic_store(slots + (blockIdx.x << 4), (unsigned)(s + 1),
                         __ATOMIC_RELAXED, __HIP_MEMORY_SCOPE_AGENT);
    // y-store after the slot store: block-private, ack overlaps the poll.
    if (L2w && s >= 1 && lane < B_SZ) {
      const size_t oidx = ((size_t)(lane * S_LEN + (s - 1))) * 1024 + j;
      y[oidx] = sv + resid[oidx];
    }
    if (wave == 0) {
      const unsigned target = (unsigned)(s + 1);
      for (;;) {
        const unsigned q0 = __hip_atomic_load(slots + ((lane      ) << 4),
                             __ATOMIC_RELAXED, __HIP_MEMORY_SCOPE_AGENT);
        const unsigned q1 = __hip_atomic_load(slots + ((lane +  64) << 4),
                             __ATOMIC_RELAXED, __HIP_MEMORY_SCOPE_AGENT);
        const unsigned q2 = __hip_atomic_load(slots + ((lane + 128) << 4),
                             __ATOMIC_RELAXED, __HIP_MEMORY_SCOPE_AGENT);
        const unsigned q3 = __hip_atomic_load(slots + ((lane + 192) << 4),
                             __ATOMIC_RELAXED, __HIP_MEMORY_SCOPE_AGENT);
        unsigned m01 = q0 < q1 ? q0 : q1;
        unsigned m23 = q2 < q3 ? q2 : q3;
        unsigned mm = m01 < m23 ? m01 : m23;
        if (__all(mm >= target)) break;
        __builtin_amdgcn_s_sleep(1);
      }
    }
    __syncthreads();
  }
}

// ---------------- column mean over S (gc = mean_t h2[b,t,:]) ----------------
__global__ __launch_bounds__(256) void colmean_kernel(
    const float* __restrict__ in, float* __restrict__ gc) {
  const int b = blockIdx.x >> 3, tc = blockIdx.x & 7;
  const int d = threadIdx.x;
  float s0 = 0.f, s1 = 0.f, s2 = 0.f, s3 = 0.f;
  const float* base = in + ((size_t)b * S_LEN + tc * 256) * D_DIM;
  for (int t = 0; t < 256; ++t) {
    const float* r = base + (size_t)t * D_DIM;
    s0 += r[d]; s1 += r[d + 256]; s2 += r[d + 512]; s3 += r[d + 768];
  }
  const float sc = 1.0f / (float)S_LEN;
  atomicAdd(&gc[b * D_DIM + d], s0 * sc);
  atomicAdd(&gc[b * D_DIM + d + 256], s1 * sc);
  atomicAdd(&gc[b * D_DIM + d + 512], s2 * sc);
  atomicAdd(&gc[b * D_DIM + d + 768], s3 * sc);
}

// ---------------- global MLP: gc(b,1024)->512->256->1, sigmoid ----------------
__global__ __launch_bounds__(256) void gmlp_kernel(
    const float* __restrict__ gc,
    const float* __restrict__ gw1, const float* __restrict__ gb1,
    const float* __restrict__ gw2, const float* __restrict__ gb2,
    const float* __restrict__ gw3, const float* __restrict__ gb3,
    float* __restrict__ gout) {
  const int b = blockIdx.x, tid = threadIdx.x;
  __shared__ float xin[1024];
  __shared__ float h1[512];
  __shared__ float h2[256];
#pragma unroll
  for (int i = 0; i < 4; ++i) xin[tid + i * 256] = gc[b * 1024 + tid + i * 256];
  __syncthreads();
  for (int o = tid; o < 512; o += 256) {
    const float* wr = gw1 + (size_t)o * 1024;
    float acc = gb1[o];
    for (int k = 0; k < 1024; k += 4) {
      const float4 wv = *(const float4*)(wr + k);
      acc += wv.x * xin[k] + wv.y * xin[k + 1] + wv.z * xin[k + 2] + wv.w * xin[k + 3];
    }
    h1[o] = gelu_f(acc);
  }
  __syncthreads();
  {
    const float* wr = gw2 + (size_t)tid * 512;
    float acc = gb2[tid];
    for (int k = 0; k < 512; k += 4) {
      const float4 wv = *(const float4*)(wr + k);
      acc += wv.x * h1[k] + wv.y * h1[k + 1] + wv.z * h1[k + 2] + wv.w * h1[k + 3];
    }
    h2[tid] = gelu_f(acc);
  }
  __syncthreads();
  float p = h2[tid] * gw3[tid];
#pragma unroll
  for (int m = 1; m < 64; m <<= 1) p += __shfl_xor(p, m, 64);
  __shared__ float rr[4];
  if ((tid & 63) == 0) rr[tid >> 6] = p;
  __syncthreads();
  if (tid == 0) gout[b] = sigmoid_f(rr[0] + rr[1] + rr[2] + rr[3] + gb3[0]);
}

// ---------------- coupling MLP final layer: (8192,256)@(256,) -> sigmoid ----------------
__global__ __launch_bounds__(256) void gemv_sig_kernel(
    const float* __restrict__ A, const float* __restrict__ w,
    const float* __restrict__ bias, float* __restrict__ out) {
  const int row = blockIdx.x * 4 + (threadIdx.x >> 6);
  const int lane = threadIdx.x & 63;
  F4 a, wv;
  a.v  = ((const float4*)(A + (size_t)row * 256))[lane];
  wv.v = ((const float4*)w)[lane];
  float p = a.f[0] * wv.f[0] + a.f[1] * wv.f[1] + a.f[2] * wv.f[2] + a.f[3] * wv.f[3];
#pragma unroll
  for (int m = 1; m < 64; m <<= 1) p += __shfl_xor(p, m, 64);
  if (lane == 0) out[row] = sigmoid_f(p + bias[0]);
}

// ---------------- mobius coupling update (in place, conjugate pairs) ----------------
__global__ __launch_bounds__(256) void mobius_kernel(
    float* __restrict__ out, const float* __restrict__ tf,
    const float* __restrict__ g, const float* __restrict__ ar,
    const float* __restrict__ res) {
  const int idx = blockIdx.x * 256 + threadIdx.x;   // over 8192*512
  const int row = idx >> 9;
  const int d = idx & 511;
  const int b = row >> 11;
  const float combined = 0.7f * g[b] + 0.3f * tf[row];
  const float coup = 0.1f + ar[0] * (combined - 0.5f) * 2.0f;
  float* base = out + (size_t)row * 1024;
  const float f = base[d], s2 = base[d + 512];
  const float sgn = (d < 256) ? 1.0f : -1.0f;
  float nf = f + sgn * coup * s2;
  float ns = s2 - sgn * coup * f;
  if (res) {
    const float* rb = res + (size_t)row * 1024;
    nf += rb[d];
    ns += rb[d + 512];
  }
  base[d] = nf;
  base[d + 512] = ns;
}

extern "C" void kernel_launch(void* const* d_in, const int* in_sizes, int n_in,
                              void* d_out, int out_size, void* d_ws, size_t ws_size,
                              hipStream_t stream) {
  (void)in_sizes; (void)n_in; (void)out_size; (void)ws_size;
  const float* x    = (const float*)d_in[0];
  const float* g1w  = (const float*)d_in[1];
  const float* g1b  = (const float*)d_in[2];
  const float* g2w  = (const float*)d_in[3];
  const float* g2b  = (const float*)d_in[4];
  const float* Wih0 = (const float*)d_in[5];
  const float* Whh0 = (const float*)d_in[6];
  const float* bih0 = (const float*)d_in[7];
  const float* bhh0 = (const float*)d_in[8];
  const float* Wih1 = (const float*)d_in[9];
  const float* Whh1 = (const float*)d_in[10];
  const float* bih1 = (const float*)d_in[11];
  const float* bhh1 = (const float*)d_in[12];
  const float* cw1 = (const float*)d_in[13]; const float* cb1 = (const float*)d_in[14];
  const float* cw2 = (const float*)d_in[15]; const float* cb2 = (const float*)d_in[16];
  const float* cw3 = (const float*)d_in[17]; const float* cb3 = (const float*)d_in[18];
  const float* cw4 = (const float*)d_in[19]; const float* cb4 = (const float*)d_in[20];
  const float* gw1 = (const float*)d_in[21]; const float* gb1 = (const float*)d_in[22];
  const float* gw2 = (const float*)d_in[23]; const float* gb2 = (const float*)d_in[24];
  const float* gw3 = (const float*)d_in[25]; const float* gb3 = (const float*)d_in[26];
  const float* ar  = (const float*)d_in[27];
  const float* fw1 = (const float*)d_in[28]; const float* fb1 = (const float*)d_in[29];
  const float* fw2 = (const float*)d_in[30]; const float* fb2 = (const float*)d_in[31];
  float* outp = (float*)d_out;

  // workspace layout (floats): A 25165824 | Bb 8388608 | small ~36936
  float* A  = (float*)d_ws;
  float* Bb = A + 25165824;
  float* small = Bb + 8388608;
  float* gc   = small;                 // 4096
  float* gbuf = small + 4096;          // 8
  float* tf   = small + 4104;          // 8192
  float* hb0  = small + 12296;         // 8192 (2x4096 ping-pong, h1)
  float* hb1  = small + 20488;         // 8192 (2x4096 ping-pong, h2)
  unsigned* slots0 = (unsigned*)(small + 28680);  // 256 slots x 16 u32 stride
  hipMemsetAsync(small, 0, (size_t)(36872 + 64) * sizeof(float), stream);

  // Block 1: LN -> input GEMM (layer-1) -> fused 2-layer pipelined GRU
  ln_kernel<<<8192, 256, 0, stream>>>(x, g1w, g1b, Bb);
  gemm_kernel<<<dim3(24, 64), 256, 0, stream>>>(Bb, 1024, Wih0, 1024, bih0, nullptr,
                                                A, 8192, 3072, 1024, 0);
  gru2_kernel<<<GRU_BLOCKS, 512, 0, stream>>>(A, Whh0, bhh0, Wih1, bih1,
                                              Whh1, bhh1, x, outp,
                                              hb0, hb1, slots0);

  // Block 2: LN -> adaptive mobius (3 cycles) ; x2 lives in outp
  ln_kernel<<<8192, 256, 0, stream>>>(outp, g2w, g2b, Bb);
  colmean_kernel<<<32, 256, 0, stream>>>(Bb, gc);
  gmlp_kernel<<<4, 256, 0, stream>>>(gc, gw1, gb1, gw2, gb2, gw3, gb3, gbuf);
  float* c1o = A;              // 8192x1024
  float* c2o = A + 12582912;   // 8192x512
  float* c3o = A + 20971520;   // 8192x256
  for (int cyc = 0; cyc < 3; ++cyc) {
    gemm_kernel<<<dim3(8, 64), 256, 0, stream>>>(Bb, 1024, cw1, 1024, cb1, nullptr,
                                                 c1o, 8192, 1024, 1024, 1);
    gemm_kernel<<<dim3(4, 64), 256, 0, stream>>>(c1o, 1024, cw2, 1024, cb2, nullptr,
                                                 c2o, 8192, 512, 1024, 1);
    gemm_kernel<<<dim3(2, 64), 256, 0, stream>>>(c2o, 512, cw3, 512, cb3, nullptr,
                                                 c3o, 8192, 256, 512, 1);
    gemv_sig_kernel<<<2048, 256, 0, stream>>>(c3o, cw4, cb4, tf);
    // final cycle fuses x3 = x2 + out
    mobius_kernel<<<16384, 256, 0, stream>>>(Bb, tf, gbuf, ar,
                                             (cyc == 2) ? outp : nullptr);
  }

  // Block 3: FFN residual, K chunked in 2 so hidden fits the A region
  for (int c = 0; c < 2; ++c) {
    gemm_kernel<<<dim3(16, 64), 256, 0, stream>>>(Bb, 1024,
        fw1 + (size_t)c * 2048 * 1024, 1024, fb1 + c * 2048, nullptr,
        A, 8192, 2048, 1024, 1);
    gemm_kernel<<<dim3(8, 64), 256, 0, stream>>>(A, 2048,
        fw2 + c * 2048, 4096, (c == 0) ? fb2 : nullptr,
        (c == 0) ? Bb : outp,
        outp, 8192, 1024, 2048, 0);
  }
}

// Round 5
// 16933.716 us; speedup vs baseline: 1.2385x; 1.2385x over previous
//
#include <hip/hip_runtime.h>
#include <math.h>

// Sizes fixed by the problem
#define D_DIM 1024
#define S_LEN 2048
#define B_SZ  4
#define GRU_BLOCKS 256   // x 512 threads (8 waves): 4 L1-waves + 4 L2-waves

union F4 { float4 v; float f[4]; };

__device__ __forceinline__ float gelu_f(float x) {
  return 0.5f * x * (1.0f + erff(x * 0.70710678118654752440f));
}
__device__ __forceinline__ float sigmoid_f(float x) {
  return __fdividef(1.0f, 1.0f + __expf(-x));
}
// fast tanh via exp: clamp keeps e^{2x} finite; |err| ~1e-7 rel.
__device__ __forceinline__ float tanh_f(float x) {
  const float xc = fminf(fmaxf(x, -15.0f), 15.0f);
  const float a = __expf(2.0f * xc);
  return __fdividef(a - 1.0f, a + 1.0f);
}

// ---------------- LayerNorm: one block per row of 1024 ----------------
__global__ __launch_bounds__(256) void ln_kernel(
    const float* __restrict__ x, const float* __restrict__ gamma,
    const float* __restrict__ beta, float* __restrict__ out) {
  const int row = blockIdx.x;
  const int tid = threadIdx.x;
  const int wave = tid >> 6, lane = tid & 63;
  const float4 v = ((const float4*)(x + (size_t)row * D_DIM))[tid];
  float s  = v.x + v.y + v.z + v.w;
  float ss = v.x * v.x + v.y * v.y + v.z * v.z + v.w * v.w;
#pragma unroll
  for (int m = 1; m < 64; m <<= 1) {
    s  += __shfl_xor(s,  m, 64);
    ss += __shfl_xor(ss, m, 64);
  }
  __shared__ float r0[4], r1[4];
  if (lane == 0) { r0[wave] = s; r1[wave] = ss; }
  __syncthreads();
  s  = r0[0] + r0[1] + r0[2] + r0[3];
  ss = r1[0] + r1[1] + r1[2] + r1[3];
  const float mean = s * (1.0f / D_DIM);
  const float var  = ss * (1.0f / D_DIM) - mean * mean;
  const float inv  = rsqrtf(var + 1e-5f);
  const float4 g4 = ((const float4*)gamma)[tid];
  const float4 b4 = ((const float4*)beta)[tid];
  float4 o;
  o.x = (v.x - mean) * inv * g4.x + b4.x;
  o.y = (v.y - mean) * inv * g4.y + b4.y;
  o.z = (v.z - mean) * inv * g4.z + b4.z;
  o.w = (v.w - mean) * inv * g4.w + b4.w;
  ((float4*)(out + (size_t)row * D_DIM))[tid] = o;
}

// ---------------- Generic SGEMM: C = A @ W^T (+bias)(+act)(+res) ----------------
#define BM 128
#define BN 128
#define BKK 8
#define TM 8
#define TN 8
__global__ __launch_bounds__(256) void gemm_kernel(
    const float* __restrict__ A, int lda,
    const float* __restrict__ W, int ldw,
    const float* __restrict__ bias,
    const float* __restrict__ res,
    float* __restrict__ C,
    int M, int N, int K, int act) {
  __shared__ float As[BKK][BM];
  __shared__ float Bs[BKK][BN];
  const int tid = threadIdx.x;
  const int bm = blockIdx.y * BM;
  const int bn = blockIdx.x * BN;
  const int tx = tid & 15;
  const int ty = tid >> 4;
  const int lrow = tid >> 1;
  const int lk = (tid & 1) * 4;
  const float* Ag = A + (size_t)(bm + lrow) * lda + lk;
  const float* Wg = W + (size_t)(bn + lrow) * ldw + lk;

  float acc[TM][TN];
#pragma unroll
  for (int i = 0; i < TM; ++i)
#pragma unroll
    for (int j = 0; j < TN; ++j) acc[i][j] = 0.0f;

  for (int k0 = 0; k0 < K; k0 += BKK) {
    const float4 av = *(const float4*)(Ag + k0);
    const float4 wv = *(const float4*)(Wg + k0);
    __syncthreads();
    As[lk + 0][lrow] = av.x; As[lk + 1][lrow] = av.y;
    As[lk + 2][lrow] = av.z; As[lk + 3][lrow] = av.w;
    Bs[lk + 0][lrow] = wv.x; Bs[lk + 1][lrow] = wv.y;
    Bs[lk + 2][lrow] = wv.z; Bs[lk + 3][lrow] = wv.w;
    __syncthreads();
#pragma unroll
    for (int k = 0; k < BKK; ++k) {
      F4 a0, a1, b0, b1;
      a0.v = *(const float4*)(&As[k][ty * TM]);
      a1.v = *(const float4*)(&As[k][ty * TM + 4]);
      b0.v = *(const float4*)(&Bs[k][tx * TN]);
      b1.v = *(const float4*)(&Bs[k][tx * TN + 4]);
      float a[TM] = {a0.f[0], a0.f[1], a0.f[2], a0.f[3],
                     a1.f[0], a1.f[1], a1.f[2], a1.f[3]};
      float b[TN] = {b0.f[0], b0.f[1], b0.f[2], b0.f[3],
                     b1.f[0], b1.f[1], b1.f[2], b1.f[3]};
#pragma unroll
      for (int i = 0; i < TM; ++i)
#pragma unroll
        for (int j = 0; j < TN; ++j) acc[i][j] += a[i] * b[j];
    }
  }

  float bs_[TN];
#pragma unroll
  for (int j = 0; j < TN; ++j) bs_[j] = bias ? bias[bn + tx * TN + j] : 0.0f;
#pragma unroll
  for (int i = 0; i < TM; ++i) {
    const size_t coff = (size_t)(bm + ty * TM + i) * N + bn + tx * TN;
    float vals[TN];
#pragma unroll
    for (int j = 0; j < TN; ++j) {
      float v = acc[i][j] + bs_[j];
      if (act == 1) v = gelu_f(v);
      vals[j] = v;
    }
    if (res) {
#pragma unroll
      for (int j = 0; j < TN; ++j) vals[j] += res[coff + j];
    }
    *(float4*)(C + coff)     = make_float4(vals[0], vals[1], vals[2], vals[3]);
    *(float4*)(C + coff + 4) = make_float4(vals[4], vals[5], vals[6], vals[7]);
  }
}

// ---------------- Fused 2-layer persistent GRU, 1-step software pipeline ----
// 256 blocks x 512 threads (8 waves). Waves 0-3: layer-1, j = bid*4+wave.
// Waves 4-7: layer-2, same j. At global step s (s = 0..2048):
//   L1 computes h1[s]   from exchange h1[s-1] (+ precomputed xi[s]).
//   L2 computes h2[s-1] from exchange h1[s-1] (folded xi2 dot) and h2[s-2].
// ROUND-5 FIX (spill): R4 kept Wih1 (48 regs) + Whh1 (48 regs) per L2 lane;
// allocator capped at 128 VGPR and spilled ~25 regs -> 20 GB/dispatch of
// symmetric scratch traffic (FETCH 8.7 GB + WRITE 10.8 GB), 8.5 us/step,
// fully bandwidth-bound on spills. Now Wih1 lives in LDS (written once at
// prologue, 12 conflict-free ds_read_b128/lane/step); L2 live set ~110 regs.
// __launch_bounds__(512,2): true occupancy is 8 waves = 2/SIMD -> 256-VGPR
// budget, so the allocator has headroom.
// Parity audit (hX[t] stored into bufX[(t+1)&1]):
//   read h1[s-1] <- buf1[s&1];   write h1[s]   -> buf1[(s+1)&1]  (disjoint)
//   read h2[s-2] <- buf2[(s+1)&1]; write h2[s-1]-> buf2[s&1]     (disjoint)
//   WAR: h1[s-1] overwritten at step s+1, after all readers passed barrier s.
// Exchange protocol (verified R3 chain, unchanged): sc0sc1 stage -> LDS ->
// compute -> relaxed AGENT h-store -> __syncthreads (drains vmcnt(0)) ->
// slot store -> gather poll -> __syncthreads.
// NO threadfence / NO acquire (round-1 lesson: wbl2/inv storm).
__global__ __launch_bounds__(512, 2) void gru2_kernel(
    const float* __restrict__ xi,    // (B,S,3H) layer-1 input GEMM (incl b_ih0)
    const float* __restrict__ Whh0,
    const float* __restrict__ bhh0,
    const float* __restrict__ Wih1,
    const float* __restrict__ bih1,
    const float* __restrict__ Whh1,
    const float* __restrict__ bhh1,
    const float* __restrict__ resid, // x
    float* __restrict__ y,           // (B,S,H): h2 + resid
    float* __restrict__ h1buf,       // 2*4096 floats, zeroed
    float* __restrict__ h2buf,       // 2*4096 floats, zeroed
    unsigned* __restrict__ slots)    // 256 slots x 16 u32 stride, zeroed
{
  const int tid = threadIdx.x;
  const int wave = tid >> 6, lane = tid & 63;
  const bool L2w = (wave >= 4);
  const int wv = wave & 3;                      // L2 sub-wave index
  const int j = (blockIdx.x << 2) + wv;         // 0..1023

  __shared__ float h1_lds[4096];
  __shared__ float h2_lds[4096];
  __shared__ float wb_lds[12288];  // Wih1 fragments: [wv][g][c][lane] float4

  // recurrent weights in registers: wa[g][c][e] = W[g*1024+j][c*256+lane*4+e]
  float wa[3][4][4];
  {
    const float* Wa = L2w ? Whh1 : Whh0;
#pragma unroll
    for (int g = 0; g < 3; ++g) {
      const float* row = Wa + (size_t)(g * 1024 + j) * 1024;
#pragma unroll
      for (int c = 0; c < 4; ++c) {
        F4 q; q.v = *(const float4*)(row + (c << 8) + (lane << 2));
#pragma unroll
        for (int e = 0; e < 4; ++e) wa[g][c][e] = q.f[e];
      }
    }
  }
  // L2: input weights Wih1 -> LDS (same k-ownership). Written once; first
  // read happens after the s=0 staging __syncthreads (ordering covered).
  if (L2w) {
#pragma unroll
    for (int g = 0; g < 3; ++g) {
      const float* row = Wih1 + (size_t)(g * 1024 + j) * 1024;
#pragma unroll
      for (int c = 0; c < 4; ++c) {
        const float4 q = *(const float4*)(row + (c << 8) + (lane << 2));
        ((float4*)wb_lds)[(((wv * 3 + g) << 2) + c) * 64 + lane] = q;
      }
    }
  }
  // biases: r=sig(xr+hr+b_r), z=sig(xz+hz+b_z), n=tanh(xn+b_in+r*(hn+b_hn))
  float b_r, b_z, b_in, b_hn;
  if (!L2w) {  // xi already contains b_ih0 (added by GEMM)
    b_r = bhh0[j]; b_z = bhh0[1024 + j]; b_in = 0.0f; b_hn = bhh0[2048 + j];
  } else {
    b_r  = bih1[j] + bhh1[j];
    b_z  = bih1[1024 + j] + bhh1[1024 + j];
    b_in = bih1[2048 + j];
    b_hn = bhh1[2048 + j];
  }

  // own-j hidden state (register, identical in all lanes of the wave)
  float hold[B_SZ] = {0.0f, 0.0f, 0.0f, 0.0f};

  // L1 xi prologue (t=0)
  float xr[B_SZ], xz[B_SZ], xn[B_SZ];
  if (!L2w) {
#pragma unroll
    for (int b = 0; b < B_SZ; ++b) {
      const float* xp = xi + ((size_t)(b * S_LEN)) * 3072 + j;
      xr[b] = xp[0]; xz[b] = xp[1024]; xn[b] = xp[2048];
    }
  }

  for (int s = 0; s <= S_LEN; ++s) {
    float* hr1 = h1buf + ((s & 1) << 12);        // h1[s-1]
    float* hw1 = h1buf + (((s + 1) & 1) << 12);  // h1[s]
    float* hr2 = h2buf + (((s + 1) & 1) << 12);  // h2[s-2]
    float* hw2 = h2buf + ((s & 1) << 12);        // h2[s-1]

    // Stage h1 (threads 0-255) and h2 (threads 256-511) into LDS.
    {
      const int tt = tid & 255;
      const float* bsrc = (tid < 256) ? hr1 : hr2;
      const float* p0 = bsrc + (tt << 2);
      float4 r0, r1, r2, r3;
      asm volatile("global_load_dwordx4 %0, %1, off sc0 sc1" : "=v"(r0) : "v"(p0));
      asm volatile("global_load_dwordx4 %0, %1, off sc0 sc1" : "=v"(r1) : "v"(p0 + 1024));
      asm volatile("global_load_dwordx4 %0, %1, off sc0 sc1" : "=v"(r2) : "v"(p0 + 2048));
      asm volatile("global_load_dwordx4 %0, %1, off sc0 sc1" : "=v"(r3) : "v"(p0 + 3072));
      asm volatile("s_waitcnt vmcnt(0)" ::: "memory");
      __builtin_amdgcn_sched_barrier(0);
      float* dl = (tid < 256) ? h1_lds : h2_lds;
      ((float4*)dl)[tt]       = r0;
      ((float4*)dl)[tt + 256] = r1;
      ((float4*)dl)[tt + 512] = r2;
      ((float4*)dl)[tt + 768] = r3;
    }
    __syncthreads();

    float hnew[B_SZ];
    float sv = 0.0f;

    if (!L2w) {
      // ---- layer 1, t = s (garbage at s=2048; stores guarded) ----
      float nxr[B_SZ], nxz[B_SZ], nxn[B_SZ];
      {
        const int tn = (s + 1 < S_LEN) ? (s + 1) : (S_LEN - 1);
#pragma unroll
        for (int b = 0; b < B_SZ; ++b) {
          const float* xp = xi + ((size_t)(b * S_LEN + tn)) * 3072 + j;
          nxr[b] = xp[0]; nxz[b] = xp[1024]; nxn[b] = xp[2048];
        }
      }
      float a0[B_SZ], a1[B_SZ], a2[B_SZ];
#pragma unroll
      for (int b = 0; b < B_SZ; ++b) {
        float s0 = 0.f, s1 = 0.f, s2 = 0.f;
#pragma unroll
        for (int c = 0; c < 4; ++c) {
          F4 q; q.v = *((const float4*)(h1_lds + (b << 10) + (c << 8)) + lane);
#pragma unroll
          for (int e = 0; e < 4; ++e) {
            s0 += wa[0][c][e] * q.f[e];
            s1 += wa[1][c][e] * q.f[e];
            s2 += wa[2][c][e] * q.f[e];
          }
        }
        a0[b] = s0; a1[b] = s1; a2[b] = s2;
      }
#pragma unroll
      for (int m = 1; m < 64; m <<= 1)
#pragma unroll
        for (int b = 0; b < B_SZ; ++b) {
          a0[b] += __shfl_xor(a0[b], m, 64);
          a1[b] += __shfl_xor(a1[b], m, 64);
          a2[b] += __shfl_xor(a2[b], m, 64);
        }
#pragma unroll
      for (int b = 0; b < B_SZ; ++b) {
        const float r = sigmoid_f(xr[b] + a0[b] + b_r);
        const float z = sigmoid_f(xz[b] + a1[b] + b_z);
        const float n = tanh_f(xn[b] + r * (a2[b] + b_hn));
        hnew[b] = (1.0f - z) * n + z * hold[b];
        if (s < S_LEN) hold[b] = hnew[b];
      }
      sv = hnew[0];
      sv = (lane == 1) ? hnew[1] : sv;
      sv = (lane == 2) ? hnew[2] : sv;
      sv = (lane == 3) ? hnew[3] : sv;
      if (s < S_LEN && lane < B_SZ)
        __hip_atomic_store(hw1 + (lane << 10) + j, sv,
                           __ATOMIC_RELAXED, __HIP_MEMORY_SCOPE_AGENT);
#pragma unroll
      for (int b = 0; b < B_SZ; ++b) {
        xr[b] = nxr[b]; xz[b] = nxz[b]; xn[b] = nxn[b];
      }
    } else {
      // ---- layer 2, t2 = s-1 (garbage at s=0; hold/stores guarded) ----
      // 24 accumulators; wb fragments read from LDS (c-outer, one read/frag).
      float xiR[B_SZ] = {0, 0, 0, 0}, xiZ[B_SZ] = {0, 0, 0, 0},
            xiN[B_SZ] = {0, 0, 0, 0}, hhR[B_SZ] = {0, 0, 0, 0},
            hhZ[B_SZ] = {0, 0, 0, 0}, hhN[B_SZ] = {0, 0, 0, 0};
#pragma unroll
      for (int c = 0; c < 4; ++c) {
        F4 w0, w1, w2;
        w0.v = ((const float4*)wb_lds)[(((wv * 3 + 0) << 2) + c) * 64 + lane];
        w1.v = ((const float4*)wb_lds)[(((wv * 3 + 1) << 2) + c) * 64 + lane];
        w2.v = ((const float4*)wb_lds)[(((wv * 3 + 2) << 2) + c) * 64 + lane];
#pragma unroll
        for (int b = 0; b < B_SZ; ++b) {
          F4 q1; q1.v = *((const float4*)(h1_lds + (b << 10) + (c << 8)) + lane);
          F4 q2; q2.v = *((const float4*)(h2_lds + (b << 10) + (c << 8)) + lane);
#pragma unroll
          for (int e = 0; e < 4; ++e) {
            xiR[b] += w0.f[e] * q1.f[e];
            xiZ[b] += w1.f[e] * q1.f[e];
            xiN[b] += w2.f[e] * q1.f[e];
            hhR[b] += wa[0][c][e] * q2.f[e];
            hhZ[b] += wa[1][c][e] * q2.f[e];
            hhN[b] += wa[2][c][e] * q2.f[e];
          }
        }
      }
      float v0[B_SZ], v1[B_SZ], v2[B_SZ], v3[B_SZ];
#pragma unroll
      for (int b = 0; b < B_SZ; ++b) {
        v0[b] = xiR[b] + hhR[b];
        v1[b] = xiZ[b] + hhZ[b];
        v2[b] = xiN[b];
        v3[b] = hhN[b];
      }
#pragma unroll
      for (int m = 1; m < 64; m <<= 1)
#pragma unroll
        for (int b = 0; b < B_SZ; ++b) {
          v0[b] += __shfl_xor(v0[b], m, 64);
          v1[b] += __shfl_xor(v1[b], m, 64);
          v2[b] += __shfl_xor(v2[b], m, 64);
          v3[b] += __shfl_xor(v3[b], m, 64);
        }
#pragma unroll
      for (int b = 0; b < B_SZ; ++b) {
        const float r = sigmoid_f(v0[b] + b_r);
        const float z = sigmoid_f(v1[b] + b_z);
        const float n = tanh_f(v2[b] + b_in + r * (v3[b] + b_hn));
        hnew[b] = (1.0f - z) * n + z * hold[b];
        if (s >= 1) hold[b] = hnew[b];
      }
      sv = hnew[0];
      sv = (lane == 1) ? hnew[1] : sv;
      sv = (lane == 2) ? hnew[2] : sv;
      sv = (lane == 3) ? hnew[3] : sv;
      if (s >= 1 && lane < B_SZ)
        __hip_atomic_store(hw2 + (lane << 10) + j, sv,
                           __ATOMIC_RELAXED, __HIP_MEMORY_SCOPE_AGENT);
    }

    // ---- device-wide barrier: slot stores + gather poll ----
    __syncthreads();  // drains vmcnt(0) per wave: all h-stores at LLC
    if (tid == 0)
      __hip_atomic_store(slots + (blockIdx.x << 4), (unsigned)(s + 1),
                         __ATOMIC_RELAXED, __HIP_MEMORY_SCOPE_AGENT);
    // y-store after the slot store: block-private, ack overlaps the poll.
    if (L2w && s >= 1 && lane < B_SZ) {
      const size_t oidx = ((size_t)(lane * S_LEN + (s - 1))) * 1024 + j;
      y[oidx] = sv + resid[oidx];
    }
    if (wave == 0) {
      const unsigned target = (unsigned)(s + 1);
      for (;;) {
        const unsigned q0 = __hip_atomic_load(slots + ((lane      ) << 4),
                             __ATOMIC_RELAXED, __HIP_MEMORY_SCOPE_AGENT);
        const unsigned q1 = __hip_atomic_load(slots + ((lane +  64) << 4),
                             __ATOMIC_RELAXED, __HIP_MEMORY_SCOPE_AGENT);
        const unsigned q2 = __hip_atomic_load(slots + ((lane + 128) << 4),
                             __ATOMIC_RELAXED, __HIP_MEMORY_SCOPE_AGENT);
        const unsigned q3 = __hip_atomic_load(slots + ((lane + 192) << 4),
                             __ATOMIC_RELAXED, __HIP_MEMORY_SCOPE_AGENT);
        unsigned m01 = q0 < q1 ? q0 : q1;
        unsigned m23 = q2 < q3 ? q2 : q3;
        unsigned mm = m01 < m23 ? m01 : m23;
        if (__all(mm >= target)) break;
        __builtin_amdgcn_s_sleep(1);
      }
    }
    __syncthreads();
  }
}

// ---------------- column mean over S (gc = mean_t h2[b,t,:]) ----------------
__global__ __launch_bounds__(256) void colmean_kernel(
    const float* __restrict__ in, float* __restrict__ gc) {
  const int b = blockIdx.x >> 3, tc = blockIdx.x & 7;
  const int d = threadIdx.x;
  float s0 = 0.f, s1 = 0.f, s2 = 0.f, s3 = 0.f;
  const float* base = in + ((size_t)b * S_LEN + tc * 256) * D_DIM;
  for (int t = 0; t < 256; ++t) {
    const float* r = base + (size_t)t * D_DIM;
    s0 += r[d]; s1 += r[d + 256]; s2 += r[d + 512]; s3 += r[d + 768];
  }
  const float sc = 1.0f / (float)S_LEN;
  atomicAdd(&gc[b * D_DIM + d], s0 * sc);
  atomicAdd(&gc[b * D_DIM + d + 256], s1 * sc);
  atomicAdd(&gc[b * D_DIM + d + 512], s2 * sc);
  atomicAdd(&gc[b * D_DIM + d + 768], s3 * sc);
}

// ---------------- global MLP: gc(b,1024)->512->256->1, sigmoid ----------------
__global__ __launch_bounds__(256) void gmlp_kernel(
    const float* __restrict__ gc,
    const float* __restrict__ gw1, const float* __restrict__ gb1,
    const float* __restrict__ gw2, const float* __restrict__ gb2,
    const float* __restrict__ gw3, const float* __restrict__ gb3,
    float* __restrict__ gout) {
  const int b = blockIdx.x, tid = threadIdx.x;
  __shared__ float xin[1024];
  __shared__ float h1[512];
  __shared__ float h2[256];
#pragma unroll
  for (int i = 0; i < 4; ++i) xin[tid + i * 256] = gc[b * 1024 + tid + i * 256];
  __syncthreads();
  for (int o = tid; o < 512; o += 256) {
    const float* wr = gw1 + (size_t)o * 1024;
    float acc = gb1[o];
    for (int k = 0; k < 1024; k += 4) {
      const float4 wv = *(const float4*)(wr + k);
      acc += wv.x * xin[k] + wv.y * xin[k + 1] + wv.z * xin[k + 2] + wv.w * xin[k + 3];
    }
    h1[o] = gelu_f(acc);
  }
  __syncthreads();
  {
    const float* wr = gw2 + (size_t)tid * 512;
    float acc = gb2[tid];
    for (int k = 0; k < 512; k += 4) {
      const float4 wv = *(const float4*)(wr + k);
      acc += wv.x * h1[k] + wv.y * h1[k + 1] + wv.z * h1[k + 2] + wv.w * h1[k + 3];
    }
    h2[tid] = gelu_f(acc);
  }
  __syncthreads();
  float p = h2[tid] * gw3[tid];
#pragma unroll
  for (int m = 1; m < 64; m <<= 1) p += __shfl_xor(p, m, 64);
  __shared__ float rr[4];
  if ((tid & 63) == 0) rr[tid >> 6] = p;
  __syncthreads();
  if (tid == 0) gout[b] = sigmoid_f(rr[0] + rr[1] + rr[2] + rr[3] + gb3[0]);
}

// ---------------- coupling MLP final layer: (8192,256)@(256,) -> sigmoid ----------------
__global__ __launch_bounds__(256) void gemv_sig_kernel(
    const float* __restrict__ A, const float* __restrict__ w,
    const float* __restrict__ bias, float* __restrict__ out) {
  const int row = blockIdx.x * 4 + (threadIdx.x >> 6);
  const int lane = threadIdx.x & 63;
  F4 a, wv;
  a.v  = ((const float4*)(A + (size_t)row * 256))[lane];
  wv.v = ((const float4*)w)[lane];
  float p = a.f[0] * wv.f[0] + a.f[1] * wv.f[1] + a.f[2] * wv.f[2] + a.f[3] * wv.f[3];
#pragma unroll
  for (int m = 1; m < 64; m <<= 1) p += __shfl_xor(p, m, 64);
  if (lane == 0) out[row] = sigmoid_f(p + bias[0]);
}

// ---------------- mobius coupling update (in place, conjugate pairs) ----------------
__global__ __launch_bounds__(256) void mobius_kernel(
    float* __restrict__ out, const float* __restrict__ tf,
    const float* __restrict__ g, const float* __restrict__ ar,
    const float* __restrict__ res) {
  const int idx = blockIdx.x * 256 + threadIdx.x;   // over 8192*512
  const int row = idx >> 9;
  const int d = idx & 511;
  const int b = row >> 11;
  const float combined = 0.7f * g[b] + 0.3f * tf[row];
  const float coup = 0.1f + ar[0] * (combined - 0.5f) * 2.0f;
  float* base = out + (size_t)row * 1024;
  const float f = base[d], s2 = base[d + 512];
  const float sgn = (d < 256) ? 1.0f : -1.0f;
  float nf = f + sgn * coup * s2;
  float ns = s2 - sgn * coup * f;
  if (res) {
    const float* rb = res + (size_t)row * 1024;
    nf += rb[d];
    ns += rb[d + 512];
  }
  base[d] = nf;
  base[d + 512] = ns;
}

extern "C" void kernel_launch(void* const* d_in, const int* in_sizes, int n_in,
                              void* d_out, int out_size, void* d_ws, size_t ws_size,
                              hipStream_t stream) {
  (void)in_sizes; (void)n_in; (void)out_size; (void)ws_size;
  const float* x    = (const float*)d_in[0];
  const float* g1w  = (const float*)d_in[1];
  const float* g1b  = (const float*)d_in[2];
  const float* g2w  = (const float*)d_in[3];
  const float* g2b  = (const float*)d_in[4];
  const float* Wih0 = (const float*)d_in[5];
  const float* Whh0 = (const float*)d_in[6];
  const float* bih0 = (const float*)d_in[7];
  const float* bhh0 = (const float*)d_in[8];
  const float* Wih1 = (const float*)d_in[9];
  const float* Whh1 = (const float*)d_in[10];
  const float* bih1 = (const float*)d_in[11];
  const float* bhh1 = (const float*)d_in[12];
  const float* cw1 = (const float*)d_in[13]; const float* cb1 = (const float*)d_in[14];
  const float* cw2 = (const float*)d_in[15]; const float* cb2 = (const float*)d_in[16];
  const float* cw3 = (const float*)d_in[17]; const float* cb3 = (const float*)d_in[18];
  const float* cw4 = (const float*)d_in[19]; const float* cb4 = (const float*)d_in[20];
  const float* gw1 = (const float*)d_in[21]; const float* gb1 = (const float*)d_in[22];
  const float* gw2 = (const float*)d_in[23]; const float* gb2 = (const float*)d_in[24];
  const float* gw3 = (const float*)d_in[25]; const float* gb3 = (const float*)d_in[26];
  const float* ar  = (const float*)d_in[27];
  const float* fw1 = (const float*)d_in[28]; const float* fb1 = (const float*)d_in[29];
  const float* fw2 = (const float*)d_in[30]; const float* fb2 = (const float*)d_in[31];
  float* outp = (float*)d_out;

  // workspace layout (floats): A 25165824 | Bb 8388608 | small ~36936
  float* A  = (float*)d_ws;
  float* Bb = A + 25165824;
  float* small = Bb + 8388608;
  float* gc   = small;                 // 4096
  float* gbuf = small + 4096;          // 8
  float* tf   = small + 4104;          // 8192
  float* hb0  = small + 12296;         // 8192 (2x4096 ping-pong, h1)
  float* hb1  = small + 20488;         // 8192 (2x4096 ping-pong, h2)
  unsigned* slots0 = (unsigned*)(small + 28680);  // 256 slots x 16 u32 stride
  hipMemsetAsync(small, 0, (size_t)(36872 + 64) * sizeof(float), stream);

  // Block 1: LN -> input GEMM (layer-1) -> fused 2-layer pipelined GRU
  ln_kernel<<<8192, 256, 0, stream>>>(x, g1w, g1b, Bb);
  gemm_kernel<<<dim3(24, 64), 256, 0, stream>>>(Bb, 1024, Wih0, 1024, bih0, nullptr,
                                                A, 8192, 3072, 1024, 0);
  gru2_kernel<<<GRU_BLOCKS, 512, 0, stream>>>(A, Whh0, bhh0, Wih1, bih1,
                                              Whh1, bhh1, x, outp,
                                              hb0, hb1, slots0);

  // Block 2: LN -> adaptive mobius (3 cycles) ; x2 lives in outp
  ln_kernel<<<8192, 256, 0, stream>>>(outp, g2w, g2b, Bb);
  colmean_kernel<<<32, 256, 0, stream>>>(Bb, gc);
  gmlp_kernel<<<4, 256, 0, stream>>>(gc, gw1, gb1, gw2, gb2, gw3, gb3, gbuf);
  float* c1o = A;              // 8192x1024
  float* c2o = A + 12582912;   // 8192x512
  float* c3o = A + 20971520;   // 8192x256
  for (int cyc = 0; cyc < 3; ++cyc) {
    gemm_kernel<<<dim3(8, 64), 256, 0, stream>>>(Bb, 1024, cw1, 1024, cb1, nullptr,
                                                 c1o, 8192, 1024, 1024, 1);
    gemm_kernel<<<dim3(4, 64), 256, 0, stream>>>(c1o, 1024, cw2, 1024, cb2, nullptr,
                                                 c2o, 8192, 512, 1024, 1);
    gemm_kernel<<<dim3(2, 64), 256, 0, stream>>>(c2o, 512, cw3, 512, cb3, nullptr,
                                                 c3o, 8192, 256, 512, 1);
    gemv_sig_kernel<<<2048, 256, 0, stream>>>(c3o, cw4, cb4, tf);
    // final cycle fuses x3 = x2 + out
    mobius_kernel<<<16384, 256, 0, stream>>>(Bb, tf, gbuf, ar,
                                             (cyc == 2) ? outp : nullptr);
  }

  // Block 3: FFN residual, K chunked in 2 so hidden fits the A region
  for (int c = 0; c < 2; ++c) {
    gemm_kernel<<<dim3(16, 64), 256, 0, stream>>>(Bb, 1024,
        fw1 + (size_t)c * 2048 * 1024, 1024, fb1 + c * 2048, nullptr,
        A, 8192, 2048, 1024, 1);
    gemm_kernel<<<dim3(8, 64), 256, 0, stream>>>(A, 2048,
        fw2 + c * 2048, 4096, (c == 0) ? fb2 : nullptr,
        (c == 0) ? Bb : outp,
        outp, 8192, 1024, 2048, 0);
  }
}

// Round 6
// 15018.295 us; speedup vs baseline: 1.3964x; 1.1275x over previous
//
#include <hip/hip_runtime.h>
#include <math.h>

// Sizes fixed by the problem
#define D_DIM 1024
#define S_LEN 2048
#define B_SZ  4
#define GRU_BLOCKS 256   // x 512 threads (8 waves); wave owns (j, 2 batches), both layers

union F4 { float4 v; float f[4]; };
typedef float v2f __attribute__((ext_vector_type(2)));
union U64 { v2f v; unsigned long long u; float f[2]; };

__device__ __forceinline__ float gelu_f(float x) {
  return 0.5f * x * (1.0f + erff(x * 0.70710678118654752440f));
}
__device__ __forceinline__ float sigmoid_f(float x) {
  return __fdividef(1.0f, 1.0f + __expf(-x));
}
// fast tanh via exp: clamp keeps e^{2x} finite; |err| ~1e-7 rel.
__device__ __forceinline__ float tanh_f(float x) {
  const float xc = fminf(fmaxf(x, -15.0f), 15.0f);
  const float a = __expf(2.0f * xc);
  return __fdividef(a - 1.0f, a + 1.0f);
}

// ---------------- LayerNorm: one block per row of 1024 ----------------
__global__ __launch_bounds__(256) void ln_kernel(
    const float* __restrict__ x, const float* __restrict__ gamma,
    const float* __restrict__ beta, float* __restrict__ out) {
  const int row = blockIdx.x;
  const int tid = threadIdx.x;
  const int wave = tid >> 6, lane = tid & 63;
  const float4 v = ((const float4*)(x + (size_t)row * D_DIM))[tid];
  float s  = v.x + v.y + v.z + v.w;
  float ss = v.x * v.x + v.y * v.y + v.z * v.z + v.w * v.w;
#pragma unroll
  for (int m = 1; m < 64; m <<= 1) {
    s  += __shfl_xor(s,  m, 64);
    ss += __shfl_xor(ss, m, 64);
  }
  __shared__ float r0[4], r1[4];
  if (lane == 0) { r0[wave] = s; r1[wave] = ss; }
  __syncthreads();
  s  = r0[0] + r0[1] + r0[2] + r0[3];
  ss = r1[0] + r1[1] + r1[2] + r1[3];
  const float mean = s * (1.0f / D_DIM);
  const float var  = ss * (1.0f / D_DIM) - mean * mean;
  const float inv  = rsqrtf(var + 1e-5f);
  const float4 g4 = ((const float4*)gamma)[tid];
  const float4 b4 = ((const float4*)beta)[tid];
  float4 o;
  o.x = (v.x - mean) * inv * g4.x + b4.x;
  o.y = (v.y - mean) * inv * g4.y + b4.y;
  o.z = (v.z - mean) * inv * g4.z + b4.z;
  o.w = (v.w - mean) * inv * g4.w + b4.w;
  ((float4*)(out + (size_t)row * D_DIM))[tid] = o;
}

// ---------------- Generic SGEMM: C = A @ W^T (+bias)(+act)(+res) ----------------
// Packed-fp32 inner loop: acc2[i][jj] += {a[i],a[i]} * b2[jj]  (v_pk_fma_f32).
#define BM 128
#define BN 128
#define BKK 8
#define TM 8
#define TN 8
__global__ __launch_bounds__(256) void gemm_kernel(
    const float* __restrict__ A, int lda,
    const float* __restrict__ W, int ldw,
    const float* __restrict__ bias,
    const float* __restrict__ res,
    float* __restrict__ C,
    int M, int N, int K, int act) {
  __shared__ float As[BKK][BM];
  __shared__ float Bs[BKK][BN];
  const int tid = threadIdx.x;
  const int bm = blockIdx.y * BM;
  const int bn = blockIdx.x * BN;
  const int tx = tid & 15;
  const int ty = tid >> 4;
  const int lrow = tid >> 1;
  const int lk = (tid & 1) * 4;
  const float* Ag = A + (size_t)(bm + lrow) * lda + lk;
  const float* Wg = W + (size_t)(bn + lrow) * ldw + lk;

  v2f acc2[TM][TN / 2];
#pragma unroll
  for (int i = 0; i < TM; ++i)
#pragma unroll
    for (int j = 0; j < TN / 2; ++j) acc2[i][j] = (v2f){0.0f, 0.0f};

  for (int k0 = 0; k0 < K; k0 += BKK) {
    const float4 av = *(const float4*)(Ag + k0);
    const float4 wv = *(const float4*)(Wg + k0);
    __syncthreads();
    As[lk + 0][lrow] = av.x; As[lk + 1][lrow] = av.y;
    As[lk + 2][lrow] = av.z; As[lk + 3][lrow] = av.w;
    Bs[lk + 0][lrow] = wv.x; Bs[lk + 1][lrow] = wv.y;
    Bs[lk + 2][lrow] = wv.z; Bs[lk + 3][lrow] = wv.w;
    __syncthreads();
#pragma unroll
    for (int k = 0; k < BKK; ++k) {
      F4 a0, a1, b0, b1;
      a0.v = *(const float4*)(&As[k][ty * TM]);
      a1.v = *(const float4*)(&As[k][ty * TM + 4]);
      b0.v = *(const float4*)(&Bs[k][tx * TN]);
      b1.v = *(const float4*)(&Bs[k][tx * TN + 4]);
      float a[TM] = {a0.f[0], a0.f[1], a0.f[2], a0.f[3],
                     a1.f[0], a1.f[1], a1.f[2], a1.f[3]};
      v2f b2[TN / 2] = {(v2f){b0.f[0], b0.f[1]}, (v2f){b0.f[2], b0.f[3]},
                        (v2f){b1.f[0], b1.f[1]}, (v2f){b1.f[2], b1.f[3]}};
#pragma unroll
      for (int i = 0; i < TM; ++i) {
        const v2f asp = (v2f){a[i], a[i]};
#pragma unroll
        for (int j = 0; j < TN / 2; ++j)
          acc2[i][j] = __builtin_elementwise_fma(asp, b2[j], acc2[i][j]);
      }
    }
  }

  float bs_[TN];
#pragma unroll
  for (int j = 0; j < TN; ++j) bs_[j] = bias ? bias[bn + tx * TN + j] : 0.0f;
#pragma unroll
  for (int i = 0; i < TM; ++i) {
    const size_t coff = (size_t)(bm + ty * TM + i) * N + bn + tx * TN;
    float vals[TN];
#pragma unroll
    for (int j = 0; j < TN / 2; ++j) {
#pragma unroll
      for (int e = 0; e < 2; ++e) {
        float v = acc2[i][j][e] + bs_[j * 2 + e];
        if (act == 1) v = gelu_f(v);
        vals[j * 2 + e] = v;
      }
    }
    if (res) {
#pragma unroll
      for (int j = 0; j < TN; ++j) vals[j] += res[coff + j];
    }
    *(float4*)(C + coff)     = make_float4(vals[0], vals[1], vals[2], vals[3]);
    *(float4*)(C + coff + 4) = make_float4(vals[4], vals[5], vals[6], vals[7]);
  }
}

// ---------------- Fused 2-layer persistent GRU, 1-step software pipeline ----
// ROUND-6 restructure: 256 blocks x 512 threads (8 waves). Wave w owns
// j = bid*4 + (w&3) and batch pair p = (w>>2)*2, computing BOTH layers for
// its 2 batches (R5 had L1-waves ~600 inst vs L2-waves ~1000 -> barrier
// waited on L2). Balanced waves; h1 LDS fragments read ONCE and reused for
// the L1 dot AND L2's xi-dot. Dots in packed fp32 (v_pk_fma_f32 via
// __builtin_elementwise_fma on float2): 288 -> 144 FMA issues/wave/step.
// Butterfly reduce packs the 2 batches of each value into one 64-bit
// __shfl_xor + one packed add (7 packed vals x 6 rounds).
// Weights: wa0=Whh0(j), wa1=Whh1(j) in regs (96 v2f regs), wb=Wih1(j) in
// LDS (R5-proven; spill watch: R4's reg overflow cost 20GB of scratch
// traffic -- if FETCH balloons again, wa1 goes to LDS too).
// Barrier: pre-slot __syncthreads (drains vmcnt(0): all h-stores at LLC)
// -> tid0 slot store -> y-stores (ack overlaps poll) -> ALL-WAVES gather
// poll (no closing __syncthreads). Safety of dropping it: a wave's poll
// success requires ALL blocks' slots >= s+1, incl. its own block, whose
// tid0 stored only after the pre-slot sync -- i.e. after every wave of
// this block finished ALL its LDS reads for step s. So overwriting the
// staging LDS at s+1 cannot race step-s readers.
// Pipeline at global step s (s = 0..2048):
//   L1 computes h1[s]   from h1[s-1] (+ precomputed xi[s]).
//   L2 computes h2[s-1] from h1[s-1] (xi-dot vs wb) and h2[s-2].
// Parity audit (hX[t] stored into bufX[(t+1)&1]):
//   read h1[s-1] <- buf1[s&1];    write h1[s]   -> buf1[(s+1)&1]  disjoint
//   read h2[s-2] <- buf2[(s+1)&1]; write h2[s-1] -> buf2[s&1]     disjoint
// Exchange protocol per R3 (verified): sc0sc1 stage -> LDS -> compute ->
// relaxed AGENT h-store -> sync(drain) -> slot -> poll.
// NO threadfence / NO acquire (round-1 lesson: wbl2/inv storm).
__global__ __launch_bounds__(512, 2) void gru2_kernel(
    const float* __restrict__ xi,    // (B,S,3H) layer-1 input GEMM (incl b_ih0)
    const float* __restrict__ Whh0,
    const float* __restrict__ bhh0,
    const float* __restrict__ Wih1,
    const float* __restrict__ bih1,
    const float* __restrict__ Whh1,
    const float* __restrict__ bhh1,
    const float* __restrict__ resid, // x
    float* __restrict__ y,           // (B,S,H): h2 + resid
    float* __restrict__ h1buf,       // 2*4096 floats, zeroed
    float* __restrict__ h2buf,       // 2*4096 floats, zeroed
    unsigned* __restrict__ slots)    // 256 slots x 16 u32 stride, zeroed
{
  const int tid = threadIdx.x;
  const int wave = tid >> 6, lane = tid & 63;
  const int jj = wave & 3;
  const int j = (blockIdx.x << 2) + jj;     // 0..1023
  const int p = (wave >> 2) << 1;           // batch base: 0 or 2

  __shared__ float h1_lds[4096];
  __shared__ float h2_lds[4096];
  __shared__ float wb_lds[12288];  // Wih1 fragments: [jj][g][c][lane] float4

  // recurrent weights (both layers) in regs, packed:
  // waX[g][c][hl] = {W[g*1024+j][c*256+lane*4 + 2hl], [.. +2hl+1]}
  v2f wa0[3][4][2], wa1[3][4][2];
#pragma unroll
  for (int g = 0; g < 3; ++g) {
#pragma unroll
    for (int c = 0; c < 4; ++c) {
      F4 q0; q0.v = *(const float4*)(Whh0 + (size_t)(g * 1024 + j) * 1024 + (c << 8) + (lane << 2));
      wa0[g][c][0] = (v2f){q0.f[0], q0.f[1]};
      wa0[g][c][1] = (v2f){q0.f[2], q0.f[3]};
      F4 q1; q1.v = *(const float4*)(Whh1 + (size_t)(g * 1024 + j) * 1024 + (c << 8) + (lane << 2));
      wa1[g][c][0] = (v2f){q1.f[0], q1.f[1]};
      wa1[g][c][1] = (v2f){q1.f[2], q1.f[3]};
    }
  }
  // wb -> LDS, written once by waves 0-3 (one wave per jj); first read is
  // after the s=0 staging __syncthreads (ordering covered).
  if (wave < 4) {
#pragma unroll
    for (int g = 0; g < 3; ++g)
#pragma unroll
      for (int c = 0; c < 4; ++c) {
        const float4 q = *(const float4*)(Wih1 + (size_t)(g * 1024 + j) * 1024 + (c << 8) + (lane << 2));
        ((float4*)wb_lds)[(((jj * 3 + g) << 2) + c) * 64 + lane] = q;
      }
  }
  // biases: r=sig(xr+hr+b_r), z=sig(xz+hz+b_z), n=tanh(xn+b_in+r*(hn+b_hn))
  const float b1r = bhh0[j], b1z = bhh0[1024 + j], b1hn = bhh0[2048 + j];
  const float b2r  = bih1[j] + bhh1[j];
  const float b2z  = bih1[1024 + j] + bhh1[1024 + j];
  const float b2in = bih1[2048 + j];
  const float b2hn = bhh1[2048 + j];

  float hold1[2] = {0.0f, 0.0f};
  float hold2[2] = {0.0f, 0.0f};

  // xi prologue (t=0) for this wave's 2 batches
  float xr[2], xz[2], xn[2];
#pragma unroll
  for (int bb = 0; bb < 2; ++bb) {
    const float* xp = xi + ((size_t)((p + bb) * S_LEN)) * 3072 + j;
    xr[bb] = xp[0]; xz[bb] = xp[1024]; xn[bb] = xp[2048];
  }

  for (int s = 0; s <= S_LEN; ++s) {
    float* hr1 = h1buf + ((s & 1) << 12);        // h1[s-1]
    float* hw1 = h1buf + (((s + 1) & 1) << 12);  // h1[s]
    float* hr2 = h2buf + (((s + 1) & 1) << 12);  // h2[s-2]
    float* hw2 = h2buf + ((s & 1) << 12);        // h2[s-1]

    // Stage h1 (threads 0-255) and h2 (threads 256-511) into LDS.
    {
      const int tt = tid & 255;
      const float* bsrc = (tid < 256) ? hr1 : hr2;
      const float* p0 = bsrc + (tt << 2);
      float4 r0, r1, r2, r3;
      asm volatile("global_load_dwordx4 %0, %1, off sc0 sc1" : "=v"(r0) : "v"(p0));
      asm volatile("global_load_dwordx4 %0, %1, off sc0 sc1" : "=v"(r1) : "v"(p0 + 1024));
      asm volatile("global_load_dwordx4 %0, %1, off sc0 sc1" : "=v"(r2) : "v"(p0 + 2048));
      asm volatile("global_load_dwordx4 %0, %1, off sc0 sc1" : "=v"(r3) : "v"(p0 + 3072));
      asm volatile("s_waitcnt vmcnt(0)" ::: "memory");
      __builtin_amdgcn_sched_barrier(0);
      float* dl = (tid < 256) ? h1_lds : h2_lds;
      ((float4*)dl)[tt]       = r0;
      ((float4*)dl)[tt + 256] = r1;
      ((float4*)dl)[tt + 512] = r2;
      ((float4*)dl)[tt + 768] = r3;
    }
    __syncthreads();

    // Next step's xi loads; latency hides under the dots.
    float nxr[2], nxz[2], nxn[2];
    {
      const int tn = (s + 1 < S_LEN) ? (s + 1) : (S_LEN - 1);
#pragma unroll
      for (int bb = 0; bb < 2; ++bb) {
        const float* xp = xi + ((size_t)((p + bb) * S_LEN + tn)) * 3072 + j;
        nxr[bb] = xp[0]; nxz[bb] = xp[1024]; nxn[bb] = xp[2048];
      }
    }

    // ---- packed dots: L1 (wa0 . h1), L2 xi (wb . h1, reusing h1 frags),
    //      L2 hh (wa1 . h2). acc[g][bb] over this lane's 16 k's.
    v2f aA[3][2], aX[3][2], aH[3][2];
#pragma unroll
    for (int g = 0; g < 3; ++g)
#pragma unroll
      for (int bb = 0; bb < 2; ++bb) {
        aA[g][bb] = (v2f){0.f, 0.f};
        aX[g][bb] = (v2f){0.f, 0.f};
        aH[g][bb] = (v2f){0.f, 0.f};
      }
#pragma unroll
    for (int c = 0; c < 4; ++c) {
      v2f wb_[3][2];
#pragma unroll
      for (int g = 0; g < 3; ++g) {
        F4 w; w.v = ((const float4*)wb_lds)[(((jj * 3 + g) << 2) + c) * 64 + lane];
        wb_[g][0] = (v2f){w.f[0], w.f[1]};
        wb_[g][1] = (v2f){w.f[2], w.f[3]};
      }
#pragma unroll
      for (int bb = 0; bb < 2; ++bb) {
        F4 q1; q1.v = *((const float4*)(h1_lds + ((p + bb) << 10) + (c << 8)) + lane);
        F4 q2; q2.v = *((const float4*)(h2_lds + ((p + bb) << 10) + (c << 8)) + lane);
        const v2f h1lo = (v2f){q1.f[0], q1.f[1]}, h1hi = (v2f){q1.f[2], q1.f[3]};
        const v2f h2lo = (v2f){q2.f[0], q2.f[1]}, h2hi = (v2f){q2.f[2], q2.f[3]};
#pragma unroll
        for (int g = 0; g < 3; ++g) {
          aA[g][bb] = __builtin_elementwise_fma(wa0[g][c][0], h1lo, aA[g][bb]);
          aA[g][bb] = __builtin_elementwise_fma(wa0[g][c][1], h1hi, aA[g][bb]);
          aX[g][bb] = __builtin_elementwise_fma(wb_[g][0],   h1lo, aX[g][bb]);
          aX[g][bb] = __builtin_elementwise_fma(wb_[g][1],   h1hi, aX[g][bb]);
          aH[g][bb] = __builtin_elementwise_fma(wa1[g][c][0], h2lo, aH[g][bb]);
          aH[g][bb] = __builtin_elementwise_fma(wa1[g][c][1], h2hi, aH[g][bb]);
        }
      }
    }
    // horizontal over k-parity, then pack the 2 batches into one v2f each:
    // L1: A0,A1,A2 ; L2: V0=xiR+hhR, V1=xiZ+hhZ, V2=xiN, V3=hhN
    v2f A0, A1, A2, V0, V1, V2, V3;
    A0 = (v2f){aA[0][0][0] + aA[0][0][1], aA[0][1][0] + aA[0][1][1]};
    A1 = (v2f){aA[1][0][0] + aA[1][0][1], aA[1][1][0] + aA[1][1][1]};
    A2 = (v2f){aA[2][0][0] + aA[2][0][1], aA[2][1][0] + aA[2][1][1]};
    V0 = (v2f){aX[0][0][0] + aX[0][0][1] + aH[0][0][0] + aH[0][0][1],
               aX[0][1][0] + aX[0][1][1] + aH[0][1][0] + aH[0][1][1]};
    V1 = (v2f){aX[1][0][0] + aX[1][0][1] + aH[1][0][0] + aH[1][0][1],
               aX[1][1][0] + aX[1][1][1] + aH[1][1][0] + aH[1][1][1]};
    V2 = (v2f){aX[2][0][0] + aX[2][0][1], aX[2][1][0] + aX[2][1][1]};
    V3 = (v2f){aH[2][0][0] + aH[2][0][1], aH[2][1][0] + aH[2][1][1]};
    // 64-lane butterfly on 7 packed values (shfl on u64 + packed add)
#pragma unroll
    for (int m = 1; m < 64; m <<= 1) {
      U64 t;
      t.v = A0; t.u = __shfl_xor(t.u, m, 64); A0 += t.v;
      t.v = A1; t.u = __shfl_xor(t.u, m, 64); A1 += t.v;
      t.v = A2; t.u = __shfl_xor(t.u, m, 64); A2 += t.v;
      t.v = V0; t.u = __shfl_xor(t.u, m, 64); V0 += t.v;
      t.v = V1; t.u = __shfl_xor(t.u, m, 64); V1 += t.v;
      t.v = V2; t.u = __shfl_xor(t.u, m, 64); V2 += t.v;
      t.v = V3; t.u = __shfl_xor(t.u, m, 64); V3 += t.v;
    }

    // ---- L1 gates (t = s), guarded at s = 2048 ----
    if (s < S_LEN) {
#pragma unroll
      for (int bb = 0; bb < 2; ++bb) {
        const float r = sigmoid_f(xr[bb] + A0[bb] + b1r);
        const float z = sigmoid_f(xz[bb] + A1[bb] + b1z);
        const float n = tanh_f(xn[bb] + r * (A2[bb] + b1hn));
        hold1[bb] = (1.0f - z) * n + z * hold1[bb];
      }
      if (lane < 2) {
        const float sv = (lane == 0) ? hold1[0] : hold1[1];
        __hip_atomic_store(hw1 + ((p + lane) << 10) + j, sv,
                           __ATOMIC_RELAXED, __HIP_MEMORY_SCOPE_AGENT);
      }
    }
    // ---- L2 gates (t2 = s-1), guarded at s = 0 ----
    if (s >= 1) {
#pragma unroll
      for (int bb = 0; bb < 2; ++bb) {
        const float r = sigmoid_f(V0[bb] + b2r);
        const float z = sigmoid_f(V1[bb] + b2z);
        const float n = tanh_f(V2[bb] + b2in + r * (V3[bb] + b2hn));
        hold2[bb] = (1.0f - z) * n + z * hold2[bb];
      }
      if (lane < 2) {
        const float sv = (lane == 0) ? hold2[0] : hold2[1];
        __hip_atomic_store(hw2 + ((p + lane) << 10) + j, sv,
                           __ATOMIC_RELAXED, __HIP_MEMORY_SCOPE_AGENT);
      }
    }

    // ---- device-wide barrier: sync(drain) -> slot -> y -> all-waves poll --
    __syncthreads();  // drains vmcnt(0) per wave: all h-stores at LLC
    if (tid == 0)
      __hip_atomic_store(slots + (blockIdx.x << 4), (unsigned)(s + 1),
                         __ATOMIC_RELAXED, __HIP_MEMORY_SCOPE_AGENT);
    if (s >= 1 && lane < 2) {  // y-store ack overlaps the poll
      const float sv = (lane == 0) ? hold2[0] : hold2[1];
      const size_t oidx = ((size_t)((p + lane) * S_LEN + (s - 1))) * 1024 + j;
      y[oidx] = sv + resid[oidx];
    }
    {
      const unsigned target = (unsigned)(s + 1);
      for (;;) {
        const unsigned q0 = __hip_atomic_load(slots + ((lane      ) << 4),
                             __ATOMIC_RELAXED, __HIP_MEMORY_SCOPE_AGENT);
        const unsigned q1 = __hip_atomic_load(slots + ((lane +  64) << 4),
                             __ATOMIC_RELAXED, __HIP_MEMORY_SCOPE_AGENT);
        const unsigned q2 = __hip_atomic_load(slots + ((lane + 128) << 4),
                             __ATOMIC_RELAXED, __HIP_MEMORY_SCOPE_AGENT);
        const unsigned q3 = __hip_atomic_load(slots + ((lane + 192) << 4),
                             __ATOMIC_RELAXED, __HIP_MEMORY_SCOPE_AGENT);
        unsigned m01 = q0 < q1 ? q0 : q1;
        unsigned m23 = q2 < q3 ? q2 : q3;
        unsigned mm = m01 < m23 ? m01 : m23;
        if (__all(mm >= target)) break;
        __builtin_amdgcn_s_sleep(1);
      }
    }
    // no closing __syncthreads (see header comment for the safety argument)

#pragma unroll
    for (int bb = 0; bb < 2; ++bb) {
      xr[bb] = nxr[bb]; xz[bb] = nxz[bb]; xn[bb] = nxn[bb];
    }
  }
}

// ---------------- column mean over S (gc = mean_t h2[b,t,:]) ----------------
__global__ __launch_bounds__(256) void colmean_kernel(
    const float* __restrict__ in, float* __restrict__ gc) {
  const int b = blockIdx.x >> 3, tc = blockIdx.x & 7;
  const int d = threadIdx.x;
  float s0 = 0.f, s1 = 0.f, s2 = 0.f, s3 = 0.f;
  const float* base = in + ((size_t)b * S_LEN + tc * 256) * D_DIM;
  for (int t = 0; t < 256; ++t) {
    const float* r = base + (size_t)t * D_DIM;
    s0 += r[d]; s1 += r[d + 256]; s2 += r[d + 512]; s3 += r[d + 768];
  }
  const float sc = 1.0f / (float)S_LEN;
  atomicAdd(&gc[b * D_DIM + d], s0 * sc);
  atomicAdd(&gc[b * D_DIM + d + 256], s1 * sc);
  atomicAdd(&gc[b * D_DIM + d + 512], s2 * sc);
  atomicAdd(&gc[b * D_DIM + d + 768], s3 * sc);
}

// ---------------- global MLP: gc(b,1024)->512->256->1, sigmoid ----------------
__global__ __launch_bounds__(256) void gmlp_kernel(
    const float* __restrict__ gc,
    const float* __restrict__ gw1, const float* __restrict__ gb1,
    const float* __restrict__ gw2, const float* __restrict__ gb2,
    const float* __restrict__ gw3, const float* __restrict__ gb3,
    float* __restrict__ gout) {
  const int b = blockIdx.x, tid = threadIdx.x;
  __shared__ float xin[1024];
  __shared__ float h1[512];
  __shared__ float h2[256];
#pragma unroll
  for (int i = 0; i < 4; ++i) xin[tid + i * 256] = gc[b * 1024 + tid + i * 256];
  __syncthreads();
  for (int o = tid; o < 512; o += 256) {
    const float* wr = gw1 + (size_t)o * 1024;
    float acc = gb1[o];
    for (int k = 0; k < 1024; k += 4) {
      const float4 wv = *(const float4*)(wr + k);
      acc += wv.x * xin[k] + wv.y * xin[k + 1] + wv.z * xin[k + 2] + wv.w * xin[k + 3];
    }
    h1[o] = gelu_f(acc);
  }
  __syncthreads();
  {
    const float* wr = gw2 + (size_t)tid * 512;
    float acc = gb2[tid];
    for (int k = 0; k < 512; k += 4) {
      const float4 wv = *(const float4*)(wr + k);
      acc += wv.x * h1[k] + wv.y * h1[k + 1] + wv.z * h1[k + 2] + wv.w * h1[k + 3];
    }
    h2[tid] = gelu_f(acc);
  }
  __syncthreads();
  float p = h2[tid] * gw3[tid];
#pragma unroll
  for (int m = 1; m < 64; m <<= 1) p += __shfl_xor(p, m, 64);
  __shared__ float rr[4];
  if ((tid & 63) == 0) rr[tid >> 6] = p;
  __syncthreads();
  if (tid == 0) gout[b] = sigmoid_f(rr[0] + rr[1] + rr[2] + rr[3] + gb3[0]);
}

// ---------------- coupling MLP final layer: (8192,256)@(256,) -> sigmoid ----------------
__global__ __launch_bounds__(256) void gemv_sig_kernel(
    const float* __restrict__ A, const float* __restrict__ w,
    const float* __restrict__ bias, float* __restrict__ out) {
  const int row = blockIdx.x * 4 + (threadIdx.x >> 6);
  const int lane = threadIdx.x & 63;
  F4 a, wv;
  a.v  = ((const float4*)(A + (size_t)row * 256))[lane];
  wv.v = ((const float4*)w)[lane];
  float p = a.f[0] * wv.f[0] + a.f[1] * wv.f[1] + a.f[2] * wv.f[2] + a.f[3] * wv.f[3];
#pragma unroll
  for (int m = 1; m < 64; m <<= 1) p += __shfl_xor(p, m, 64);
  if (lane == 0) out[row] = sigmoid_f(p + bias[0]);
}

// ---------------- mobius coupling update (in place, conjugate pairs) ----------------
__global__ __launch_bounds__(256) void mobius_kernel(
    float* __restrict__ out, const float* __restrict__ tf,
    const float* __restrict__ g, const float* __restrict__ ar,
    const float* __restrict__ res) {
  const int idx = blockIdx.x * 256 + threadIdx.x;   // over 8192*512
  const int row = idx >> 9;
  const int d = idx & 511;
  const int b = row >> 11;
  const float combined = 0.7f * g[b] + 0.3f * tf[row];
  const float coup = 0.1f + ar[0] * (combined - 0.5f) * 2.0f;
  float* base = out + (size_t)row * 1024;
  const float f = base[d], s2 = base[d + 512];
  const float sgn = (d < 256) ? 1.0f : -1.0f;
  float nf = f + sgn * coup * s2;
  float ns = s2 - sgn * coup * f;
  if (res) {
    const float* rb = res + (size_t)row * 1024;
    nf += rb[d];
    ns += rb[d + 512];
  }
  base[d] = nf;
  base[d + 512] = ns;
}

extern "C" void kernel_launch(void* const* d_in, const int* in_sizes, int n_in,
                              void* d_out, int out_size, void* d_ws, size_t ws_size,
                              hipStream_t stream) {
  (void)in_sizes; (void)n_in; (void)out_size; (void)ws_size;
  const float* x    = (const float*)d_in[0];
  const float* g1w  = (const float*)d_in[1];
  const float* g1b  = (const float*)d_in[2];
  const float* g2w  = (const float*)d_in[3];
  const float* g2b  = (const float*)d_in[4];
  const float* Wih0 = (const float*)d_in[5];
  const float* Whh0 = (const float*)d_in[6];
  const float* bih0 = (const float*)d_in[7];
  const float* bhh0 = (const float*)d_in[8];
  const float* Wih1 = (const float*)d_in[9];
  const float* Whh1 = (const float*)d_in[10];
  const float* bih1 = (const float*)d_in[11];
  const float* bhh1 = (const float*)d_in[12];
  const float* cw1 = (const float*)d_in[13]; const float* cb1 = (const float*)d_in[14];
  const float* cw2 = (const float*)d_in[15]; const float* cb2 = (const float*)d_in[16];
  const float* cw3 = (const float*)d_in[17]; const float* cb3 = (const float*)d_in[18];
  const float* cw4 = (const float*)d_in[19]; const float* cb4 = (const float*)d_in[20];
  const float* gw1 = (const float*)d_in[21]; const float* gb1 = (const float*)d_in[22];
  const float* gw2 = (const float*)d_in[23]; const float* gb2 = (const float*)d_in[24];
  const float* gw3 = (const float*)d_in[25]; const float* gb3 = (const float*)d_in[26];
  const float* ar  = (const float*)d_in[27];
  const float* fw1 = (const float*)d_in[28]; const float* fb1 = (const float*)d_in[29];
  const float* fw2 = (const float*)d_in[30]; const float* fb2 = (const float*)d_in[31];
  float* outp = (float*)d_out;

  // workspace layout (floats): A 25165824 | Bb 8388608 | small ~36936
  float* A  = (float*)d_ws;
  float* Bb = A + 25165824;
  float* small = Bb + 8388608;
  float* gc   = small;                 // 4096
  float* gbuf = small + 4096;          // 8
  float* tf   = small + 4104;          // 8192
  float* hb0  = small + 12296;         // 8192 (2x4096 ping-pong, h1)
  float* hb1  = small + 20488;         // 8192 (2x4096 ping-pong, h2)
  unsigned* slots0 = (unsigned*)(small + 28680);  // 256 slots x 16 u32 stride
  hipMemsetAsync(small, 0, (size_t)(36872 + 64) * sizeof(float), stream);

  // Block 1: LN -> input GEMM (layer-1) -> fused 2-layer pipelined GRU
  ln_kernel<<<8192, 256, 0, stream>>>(x, g1w, g1b, Bb);
  gemm_kernel<<<dim3(24, 64), 256, 0, stream>>>(Bb, 1024, Wih0, 1024, bih0, nullptr,
                                                A, 8192, 3072, 1024, 0);
  gru2_kernel<<<GRU_BLOCKS, 512, 0, stream>>>(A, Whh0, bhh0, Wih1, bih1,
                                              Whh1, bhh1, x, outp,
                                              hb0, hb1, slots0);

  // Block 2: LN -> adaptive mobius (3 cycles) ; x2 lives in outp
  ln_kernel<<<8192, 256, 0, stream>>>(outp, g2w, g2b, Bb);
  colmean_kernel<<<32, 256, 0, stream>>>(Bb, gc);
  gmlp_kernel<<<4, 256, 0, stream>>>(gc, gw1, gb1, gw2, gb2, gw3, gb3, gbuf);
  float* c1o = A;              // 8192x1024
  float* c2o = A + 12582912;   // 8192x512
  float* c3o = A + 20971520;   // 8192x256
  for (int cyc = 0; cyc < 3; ++cyc) {
    gemm_kernel<<<dim3(8, 64), 256, 0, stream>>>(Bb, 1024, cw1, 1024, cb1, nullptr,
                                                 c1o, 8192, 1024, 1024, 1);
    gemm_kernel<<<dim3(4, 64), 256, 0, stream>>>(c1o, 1024, cw2, 1024, cb2, nullptr,
                                                 c2o, 8192, 512, 1024, 1);
    gemm_kernel<<<dim3(2, 64), 256, 0, stream>>>(c2o, 512, cw3, 512, cb3, nullptr,
                                                 c3o, 8192, 256, 512, 1);
    gemv_sig_kernel<<<2048, 256, 0, stream>>>(c3o, cw4, cb4, tf);
    // final cycle fuses x3 = x2 + out
    mobius_kernel<<<16384, 256, 0, stream>>>(Bb, tf, gbuf, ar,
                                             (cyc == 2) ? outp : nullptr);
  }

  // Block 3: FFN residual, K chunked in 2 so hidden fits the A region
  for (int c = 0; c < 2; ++c) {
    gemm_kernel<<<dim3(16, 64), 256, 0, stream>>>(Bb, 1024,
        fw1 + (size_t)c * 2048 * 1024, 1024, fb1 + c * 2048, nullptr,
        A, 8192, 2048, 1024, 1);
    gemm_kernel<<<dim3(8, 64), 256, 0, stream>>>(A, 2048,
        fw2 + c * 2048, 4096, (c == 0) ? fb2 : nullptr,
        (c == 0) ? Bb : outp,
        outp, 8192, 1024, 2048, 0);
  }
}

// Round 7
// 13450.777 us; speedup vs baseline: 1.5592x; 1.1165x over previous
//
#include <hip/hip_runtime.h>
#include <math.h>

// Sizes fixed by the problem
#define D_DIM 1024
#define S_LEN 2048
#define B_SZ  4
#define GRU_BLOCKS 256   // 2 independent groups of 128; wave owns (j, 2 batches), both layers

union F4 { float4 v; float f[4]; };
typedef float v2f __attribute__((ext_vector_type(2)));
union U64 { v2f v; unsigned long long u; float f[2]; };

__device__ __forceinline__ float gelu_f(float x) {
  return 0.5f * x * (1.0f + erff(x * 0.70710678118654752440f));
}
__device__ __forceinline__ float sigmoid_f(float x) {
  return __fdividef(1.0f, 1.0f + __expf(-x));
}
// fast tanh via exp: clamp keeps e^{2x} finite; |err| ~1e-7 rel.
__device__ __forceinline__ float tanh_f(float x) {
  const float xc = fminf(fmaxf(x, -15.0f), 15.0f);
  const float a = __expf(2.0f * xc);
  return __fdividef(a - 1.0f, a + 1.0f);
}

// ---------------- LayerNorm: one block per row of 1024 ----------------
__global__ __launch_bounds__(256) void ln_kernel(
    const float* __restrict__ x, const float* __restrict__ gamma,
    const float* __restrict__ beta, float* __restrict__ out) {
  const int row = blockIdx.x;
  const int tid = threadIdx.x;
  const int wave = tid >> 6, lane = tid & 63;
  const float4 v = ((const float4*)(x + (size_t)row * D_DIM))[tid];
  float s  = v.x + v.y + v.z + v.w;
  float ss = v.x * v.x + v.y * v.y + v.z * v.z + v.w * v.w;
#pragma unroll
  for (int m = 1; m < 64; m <<= 1) {
    s  += __shfl_xor(s,  m, 64);
    ss += __shfl_xor(ss, m, 64);
  }
  __shared__ float r0[4], r1[4];
  if (lane == 0) { r0[wave] = s; r1[wave] = ss; }
  __syncthreads();
  s  = r0[0] + r0[1] + r0[2] + r0[3];
  ss = r1[0] + r1[1] + r1[2] + r1[3];
  const float mean = s * (1.0f / D_DIM);
  const float var  = ss * (1.0f / D_DIM) - mean * mean;
  const float inv  = rsqrtf(var + 1e-5f);
  const float4 g4 = ((const float4*)gamma)[tid];
  const float4 b4 = ((const float4*)beta)[tid];
  float4 o;
  o.x = (v.x - mean) * inv * g4.x + b4.x;
  o.y = (v.y - mean) * inv * g4.y + b4.y;
  o.z = (v.z - mean) * inv * g4.z + b4.z;
  o.w = (v.w - mean) * inv * g4.w + b4.w;
  ((float4*)(out + (size_t)row * D_DIM))[tid] = o;
}

// ---------------- Generic SGEMM: C = A @ W^T (+bias)(+act)(+res) ----------------
// Packed-fp32 inner loop: acc2[i][jj] += {a[i],a[i]} * b2[jj]  (v_pk_fma_f32).
#define BM 128
#define BN 128
#define BKK 8
#define TM 8
#define TN 8
__global__ __launch_bounds__(256) void gemm_kernel(
    const float* __restrict__ A, int lda,
    const float* __restrict__ W, int ldw,
    const float* __restrict__ bias,
    const float* __restrict__ res,
    float* __restrict__ C,
    int M, int N, int K, int act) {
  __shared__ float As[BKK][BM];
  __shared__ float Bs[BKK][BN];
  const int tid = threadIdx.x;
  const int bm = blockIdx.y * BM;
  const int bn = blockIdx.x * BN;
  const int tx = tid & 15;
  const int ty = tid >> 4;
  const int lrow = tid >> 1;
  const int lk = (tid & 1) * 4;
  const float* Ag = A + (size_t)(bm + lrow) * lda + lk;
  const float* Wg = W + (size_t)(bn + lrow) * ldw + lk;

  v2f acc2[TM][TN / 2];
#pragma unroll
  for (int i = 0; i < TM; ++i)
#pragma unroll
    for (int j = 0; j < TN / 2; ++j) acc2[i][j] = (v2f){0.0f, 0.0f};

  for (int k0 = 0; k0 < K; k0 += BKK) {
    const float4 av = *(const float4*)(Ag + k0);
    const float4 wv = *(const float4*)(Wg + k0);
    __syncthreads();
    As[lk + 0][lrow] = av.x; As[lk + 1][lrow] = av.y;
    As[lk + 2][lrow] = av.z; As[lk + 3][lrow] = av.w;
    Bs[lk + 0][lrow] = wv.x; Bs[lk + 1][lrow] = wv.y;
    Bs[lk + 2][lrow] = wv.z; Bs[lk + 3][lrow] = wv.w;
    __syncthreads();
#pragma unroll
    for (int k = 0; k < BKK; ++k) {
      F4 a0, a1, b0, b1;
      a0.v = *(const float4*)(&As[k][ty * TM]);
      a1.v = *(const float4*)(&As[k][ty * TM + 4]);
      b0.v = *(const float4*)(&Bs[k][tx * TN]);
      b1.v = *(const float4*)(&Bs[k][tx * TN + 4]);
      float a[TM] = {a0.f[0], a0.f[1], a0.f[2], a0.f[3],
                     a1.f[0], a1.f[1], a1.f[2], a1.f[3]};
      v2f b2[TN / 2] = {(v2f){b0.f[0], b0.f[1]}, (v2f){b0.f[2], b0.f[3]},
                        (v2f){b1.f[0], b1.f[1]}, (v2f){b1.f[2], b1.f[3]}};
#pragma unroll
      for (int i = 0; i < TM; ++i) {
        const v2f asp = (v2f){a[i], a[i]};
#pragma unroll
        for (int j = 0; j < TN / 2; ++j)
          acc2[i][j] = __builtin_elementwise_fma(asp, b2[j], acc2[i][j]);
      }
    }
  }

  float bs_[TN];
#pragma unroll
  for (int j = 0; j < TN; ++j) bs_[j] = bias ? bias[bn + tx * TN + j] : 0.0f;
#pragma unroll
  for (int i = 0; i < TM; ++i) {
    const size_t coff = (size_t)(bm + ty * TM + i) * N + bn + tx * TN;
    float vals[TN];
#pragma unroll
    for (int j = 0; j < TN / 2; ++j) {
#pragma unroll
      for (int e = 0; e < 2; ++e) {
        float v = acc2[i][j][e] + bs_[j * 2 + e];
        if (act == 1) v = gelu_f(v);
        vals[j * 2 + e] = v;
      }
    }
    if (res) {
#pragma unroll
      for (int j = 0; j < TN; ++j) vals[j] += res[coff + j];
    }
    *(float4*)(C + coff)     = make_float4(vals[0], vals[1], vals[2], vals[3]);
    *(float4*)(C + coff + 4) = make_float4(vals[4], vals[5], vals[6], vals[7]);
  }
}

// ---------------- Fused 2-layer persistent GRU, 1-step software pipeline ----
// ROUND-7: two INDEPENDENT batch-groups. Batches never interact in a GRU,
// so blocks 0-127 (group 0) run batches {0,1} and blocks 128-255 (group 1)
// run batches {2,3}; each group covers all 1024 j (8 waves/block, wave owns
// j = gbid*8+wave, both layers, its group's 2 batches -- per-wave work
// identical to R6). Each group barriers ONLY among its own 128 blocks
// (own slot array) and stages only its 2 batches: staging 8MB -> 4MB/step,
// poll domain + straggler skew halved.
// Wave-0-only poll + LDS-flag release (R6 had all 8 waves polling 256
// slots each -> the poll spin dominated LLC request rate AND VALUBusy):
// wave 0 polls the 128 group slots (2 loads/lane), then ds_writes flag=s+1;
// waves 1-7 spin on the LDS flag (no LLC traffic). Safety: flag is written
// only after poll success, which requires THIS block's slot=s+1, which was
// stored only after the pre-slot __syncthreads -- i.e. after every wave
// finished its step-s LDS reads. So staging overwrite at s+1 cannot race.
// Pipeline at global step s (s = 0..2048):
//   L1 computes h1[s]   from h1[s-1] (+ precomputed xi[s]).
//   L2 computes h2[s-1] from h1[s-1] (xi-dot vs wb in LDS) and h2[s-2].
// Parity audit (hX[t] stored into bufX[(t+1)&1]):
//   read h1[s-1] <- buf1[s&1];    write h1[s]   -> buf1[(s+1)&1]  disjoint
//   read h2[s-2] <- buf2[(s+1)&1]; write h2[s-1] -> buf2[s&1]     disjoint
// Exchange protocol per R3 (verified): sc0sc1 stage -> LDS -> compute ->
// relaxed AGENT h-store -> sync(drain vmcnt(0)) -> slot -> poll/flag.
// NO threadfence / NO acquire (round-1 lesson: wbl2/inv storm).
// Dots in packed fp32 (v_pk_fma_f32); butterfly reduce on 7 packed u64.
// Weights: wa0=Whh0(j), wa1=Whh1(j) in regs; wb=Wih1(j) in LDS (R5: regs
// spilled at 20GB scratch traffic; LDS version proven).
__global__ __launch_bounds__(512, 2) void gru2_kernel(
    const float* __restrict__ xi,    // (B,S,3H) layer-1 input GEMM (incl b_ih0)
    const float* __restrict__ Whh0,
    const float* __restrict__ bhh0,
    const float* __restrict__ Wih1,
    const float* __restrict__ bih1,
    const float* __restrict__ Whh1,
    const float* __restrict__ bhh1,
    const float* __restrict__ resid, // x
    float* __restrict__ y,           // (B,S,H): h2 + resid
    float* __restrict__ h1buf,       // 2*4096 floats, zeroed
    float* __restrict__ h2buf,       // 2*4096 floats, zeroed
    unsigned* __restrict__ slots)    // 2 groups x 128 slots x 16 u32, zeroed
{
  const int tid = threadIdx.x;
  const int wave = tid >> 6, lane = tid & 63;
  const int gid  = blockIdx.x >> 7;         // batch group: 0 or 1
  const int gbid = blockIdx.x & 127;        // block id within group
  const int j = (gbid << 3) + wave;         // 0..1023 (one j per wave)
  const int p = gid << 1;                   // batch base: 0 or 2
  unsigned* myslots = slots + (gid << 11);  // 128 slots x 16 u32 per group

  __shared__ float h1_lds[2048];       // this group's 2 batches of h1[s-1]
  __shared__ float h2_lds[2048];       // this group's 2 batches of h2[s-2]
  __shared__ float wb_lds[24576];      // Wih1 frags: [wave][g][c][lane] float4
  __shared__ unsigned flag;            // intra-block release

  if (tid == 0) flag = 0u;

  // recurrent weights (both layers) in regs, packed:
  // waX[g][c][hl] = {W[g*1024+j][c*256+lane*4 + 2hl], [.. +2hl+1]}
  v2f wa0[3][4][2], wa1[3][4][2];
#pragma unroll
  for (int g = 0; g < 3; ++g) {
#pragma unroll
    for (int c = 0; c < 4; ++c) {
      F4 q0; q0.v = *(const float4*)(Whh0 + (size_t)(g * 1024 + j) * 1024 + (c << 8) + (lane << 2));
      wa0[g][c][0] = (v2f){q0.f[0], q0.f[1]};
      wa0[g][c][1] = (v2f){q0.f[2], q0.f[3]};
      F4 q1; q1.v = *(const float4*)(Whh1 + (size_t)(g * 1024 + j) * 1024 + (c << 8) + (lane << 2));
      wa1[g][c][0] = (v2f){q1.f[0], q1.f[1]};
      wa1[g][c][1] = (v2f){q1.f[2], q1.f[3]};
    }
  }
  // wb -> LDS, each wave writes its own j's fragments; first read is after
  // the s=0 staging __syncthreads (ordering covered).
#pragma unroll
  for (int g = 0; g < 3; ++g)
#pragma unroll
    for (int c = 0; c < 4; ++c) {
      const float4 q = *(const float4*)(Wih1 + (size_t)(g * 1024 + j) * 1024 + (c << 8) + (lane << 2));
      ((float4*)wb_lds)[(((wave * 3 + g) << 2) + c) * 64 + lane] = q;
    }
  // biases: r=sig(xr+hr+b_r), z=sig(xz+hz+b_z), n=tanh(xn+b_in+r*(hn+b_hn))
  const float b1r = bhh0[j], b1z = bhh0[1024 + j], b1hn = bhh0[2048 + j];
  const float b2r  = bih1[j] + bhh1[j];
  const float b2z  = bih1[1024 + j] + bhh1[1024 + j];
  const float b2in = bih1[2048 + j];
  const float b2hn = bhh1[2048 + j];

  float hold1[2] = {0.0f, 0.0f};
  float hold2[2] = {0.0f, 0.0f};

  // xi prologue (t=0) for this wave's 2 batches
  float xr[2], xz[2], xn[2];
#pragma unroll
  for (int bb = 0; bb < 2; ++bb) {
    const float* xp = xi + ((size_t)((p + bb) * S_LEN)) * 3072 + j;
    xr[bb] = xp[0]; xz[bb] = xp[1024]; xn[bb] = xp[2048];
  }

  for (int s = 0; s <= S_LEN; ++s) {
    float* hr1 = h1buf + ((s & 1) << 12);        // h1[s-1]
    float* hw1 = h1buf + (((s + 1) & 1) << 12);  // h1[s]
    float* hr2 = h2buf + (((s + 1) & 1) << 12);  // h2[s-2]
    float* hw2 = h2buf + ((s & 1) << 12);        // h2[s-1]

    // Stage this group's h1 (threads 0-255) and h2 (threads 256-511):
    // 2 batches x 1024 floats each = 2 coherent dwordx4 per thread.
    {
      const int tt = tid & 255;
      const float* bsrc = ((tid < 256) ? hr1 : hr2) + (p << 10) + (tt << 2);
      float4 r0, r1;
      asm volatile("global_load_dwordx4 %0, %1, off sc0 sc1" : "=v"(r0) : "v"(bsrc));
      asm volatile("global_load_dwordx4 %0, %1, off sc0 sc1" : "=v"(r1) : "v"(bsrc + 1024));
      asm volatile("s_waitcnt vmcnt(0)" ::: "memory");
      __builtin_amdgcn_sched_barrier(0);
      float* dl = (tid < 256) ? h1_lds : h2_lds;
      ((float4*)dl)[tt]       = r0;
      ((float4*)dl)[tt + 256] = r1;
    }
    __syncthreads();

    // Next step's xi loads; latency hides under the dots.
    float nxr[2], nxz[2], nxn[2];
    {
      const int tn = (s + 1 < S_LEN) ? (s + 1) : (S_LEN - 1);
#pragma unroll
      for (int bb = 0; bb < 2; ++bb) {
        const float* xp = xi + ((size_t)((p + bb) * S_LEN + tn)) * 3072 + j;
        nxr[bb] = xp[0]; nxz[bb] = xp[1024]; nxn[bb] = xp[2048];
      }
    }

    // ---- packed dots: L1 (wa0 . h1), L2 xi (wb . h1, reusing h1 frags),
    //      L2 hh (wa1 . h2). acc[g][bb] over this lane's 16 k's.
    v2f aA[3][2], aX[3][2], aH[3][2];
#pragma unroll
    for (int g = 0; g < 3; ++g)
#pragma unroll
      for (int bb = 0; bb < 2; ++bb) {
        aA[g][bb] = (v2f){0.f, 0.f};
        aX[g][bb] = (v2f){0.f, 0.f};
        aH[g][bb] = (v2f){0.f, 0.f};
      }
#pragma unroll
    for (int c = 0; c < 4; ++c) {
      v2f wb_[3][2];
#pragma unroll
      for (int g = 0; g < 3; ++g) {
        F4 w; w.v = ((const float4*)wb_lds)[(((wave * 3 + g) << 2) + c) * 64 + lane];
        wb_[g][0] = (v2f){w.f[0], w.f[1]};
        wb_[g][1] = (v2f){w.f[2], w.f[3]};
      }
#pragma unroll
      for (int bb = 0; bb < 2; ++bb) {
        F4 q1; q1.v = *((const float4*)(h1_lds + (bb << 10) + (c << 8)) + lane);
        F4 q2; q2.v = *((const float4*)(h2_lds + (bb << 10) + (c << 8)) + lane);
        const v2f h1lo = (v2f){q1.f[0], q1.f[1]}, h1hi = (v2f){q1.f[2], q1.f[3]};
        const v2f h2lo = (v2f){q2.f[0], q2.f[1]}, h2hi = (v2f){q2.f[2], q2.f[3]};
#pragma unroll
        for (int g = 0; g < 3; ++g) {
          aA[g][bb] = __builtin_elementwise_fma(wa0[g][c][0], h1lo, aA[g][bb]);
          aA[g][bb] = __builtin_elementwise_fma(wa0[g][c][1], h1hi, aA[g][bb]);
          aX[g][bb] = __builtin_elementwise_fma(wb_[g][0],   h1lo, aX[g][bb]);
          aX[g][bb] = __builtin_elementwise_fma(wb_[g][1],   h1hi, aX[g][bb]);
          aH[g][bb] = __builtin_elementwise_fma(wa1[g][c][0], h2lo, aH[g][bb]);
          aH[g][bb] = __builtin_elementwise_fma(wa1[g][c][1], h2hi, aH[g][bb]);
        }
      }
    }
    // horizontal over k-parity, pack the 2 batches into one v2f each:
    // L1: A0,A1,A2 ; L2: V0=xiR+hhR, V1=xiZ+hhZ, V2=xiN, V3=hhN
    v2f A0, A1, A2, V0, V1, V2, V3;
    A0 = (v2f){aA[0][0][0] + aA[0][0][1], aA[0][1][0] + aA[0][1][1]};
    A1 = (v2f){aA[1][0][0] + aA[1][0][1], aA[1][1][0] + aA[1][1][1]};
    A2 = (v2f){aA[2][0][0] + aA[2][0][1], aA[2][1][0] + aA[2][1][1]};
    V0 = (v2f){aX[0][0][0] + aX[0][0][1] + aH[0][0][0] + aH[0][0][1],
               aX[0][1][0] + aX[0][1][1] + aH[0][1][0] + aH[0][1][1]};
    V1 = (v2f){aX[1][0][0] + aX[1][0][1] + aH[1][0][0] + aH[1][0][1],
               aX[1][1][0] + aX[1][1][1] + aH[1][1][0] + aH[1][1][1]};
    V2 = (v2f){aX[2][0][0] + aX[2][0][1], aX[2][1][0] + aX[2][1][1]};
    V3 = (v2f){aH[2][0][0] + aH[2][0][1], aH[2][1][0] + aH[2][1][1]};
    // 64-lane butterfly on 7 packed values (shfl on u64 + packed add)
#pragma unroll
    for (int m = 1; m < 64; m <<= 1) {
      U64 t;
      t.v = A0; t.u = __shfl_xor(t.u, m, 64); A0 += t.v;
      t.v = A1; t.u = __shfl_xor(t.u, m, 64); A1 += t.v;
      t.v = A2; t.u = __shfl_xor(t.u, m, 64); A2 += t.v;
      t.v = V0; t.u = __shfl_xor(t.u, m, 64); V0 += t.v;
      t.v = V1; t.u = __shfl_xor(t.u, m, 64); V1 += t.v;
      t.v = V2; t.u = __shfl_xor(t.u, m, 64); V2 += t.v;
      t.v = V3; t.u = __shfl_xor(t.u, m, 64); V3 += t.v;
    }

    // ---- L1 gates (t = s), guarded at s = 2048 ----
    if (s < S_LEN) {
#pragma unroll
      for (int bb = 0; bb < 2; ++bb) {
        const float r = sigmoid_f(xr[bb] + A0[bb] + b1r);
        const float z = sigmoid_f(xz[bb] + A1[bb] + b1z);
        const float n = tanh_f(xn[bb] + r * (A2[bb] + b1hn));
        hold1[bb] = (1.0f - z) * n + z * hold1[bb];
      }
      if (lane < 2) {
        const float sv = (lane == 0) ? hold1[0] : hold1[1];
        __hip_atomic_store(hw1 + ((p + lane) << 10) + j, sv,
                           __ATOMIC_RELAXED, __HIP_MEMORY_SCOPE_AGENT);
      }
    }
    // ---- L2 gates (t2 = s-1), guarded at s = 0 ----
    if (s >= 1) {
#pragma unroll
      for (int bb = 0; bb < 2; ++bb) {
        const float r = sigmoid_f(V0[bb] + b2r);
        const float z = sigmoid_f(V1[bb] + b2z);
        const float n = tanh_f(V2[bb] + b2in + r * (V3[bb] + b2hn));
        hold2[bb] = (1.0f - z) * n + z * hold2[bb];
      }
      if (lane < 2) {
        const float sv = (lane == 0) ? hold2[0] : hold2[1];
        __hip_atomic_store(hw2 + ((p + lane) << 10) + j, sv,
                           __ATOMIC_RELAXED, __HIP_MEMORY_SCOPE_AGENT);
      }
    }

    // ---- group-wide barrier: sync(drain) -> slot -> y -> poll/flag ----
    __syncthreads();  // drains vmcnt(0) per wave: all h-stores at LLC
    if (tid == 0)
      __hip_atomic_store(myslots + (gbid << 4), (unsigned)(s + 1),
                         __ATOMIC_RELAXED, __HIP_MEMORY_SCOPE_AGENT);
    if (s >= 1 && lane < 2) {  // y-store ack overlaps the poll
      const float sv = (lane == 0) ? hold2[0] : hold2[1];
      const size_t oidx = ((size_t)((p + lane) * S_LEN + (s - 1))) * 1024 + j;
      y[oidx] = sv + resid[oidx];
    }
    {
      const unsigned target = (unsigned)(s + 1);
      if (wave == 0) {
        for (;;) {
          const unsigned q0 = __hip_atomic_load(myslots + ((lane     ) << 4),
                               __ATOMIC_RELAXED, __HIP_MEMORY_SCOPE_AGENT);
          const unsigned q1 = __hip_atomic_load(myslots + ((lane + 64) << 4),
                               __ATOMIC_RELAXED, __HIP_MEMORY_SCOPE_AGENT);
          const unsigned mm = q0 < q1 ? q0 : q1;
          if (__all(mm >= target)) break;
          __builtin_amdgcn_s_sleep(1);
        }
        __hip_atomic_store(&flag, target, __ATOMIC_RELAXED,
                           __HIP_MEMORY_SCOPE_WORKGROUP);
      } else {
        while (__hip_atomic_load(&flag, __ATOMIC_RELAXED,
                                 __HIP_MEMORY_SCOPE_WORKGROUP) < target) {}
      }
    }
    // no closing __syncthreads (flag release: see header safety argument)

#pragma unroll
    for (int bb = 0; bb < 2; ++bb) {
      xr[bb] = nxr[bb]; xz[bb] = nxz[bb]; xn[bb] = nxn[bb];
    }
  }
}

// ---------------- column mean over S (gc = mean_t h2[b,t,:]) ----------------
__global__ __launch_bounds__(256) void colmean_kernel(
    const float* __restrict__ in, float* __restrict__ gc) {
  const int b = blockIdx.x >> 3, tc = blockIdx.x & 7;
  const int d = threadIdx.x;
  float s0 = 0.f, s1 = 0.f, s2 = 0.f, s3 = 0.f;
  const float* base = in + ((size_t)b * S_LEN + tc * 256) * D_DIM;
  for (int t = 0; t < 256; ++t) {
    const float* r = base + (size_t)t * D_DIM;
    s0 += r[d]; s1 += r[d + 256]; s2 += r[d + 512]; s3 += r[d + 768];
  }
  const float sc = 1.0f / (float)S_LEN;
  atomicAdd(&gc[b * D_DIM + d], s0 * sc);
  atomicAdd(&gc[b * D_DIM + d + 256], s1 * sc);
  atomicAdd(&gc[b * D_DIM + d + 512], s2 * sc);
  atomicAdd(&gc[b * D_DIM + d + 768], s3 * sc);
}

// ---------------- global MLP: gc(b,1024)->512->256->1, sigmoid ----------------
__global__ __launch_bounds__(256) void gmlp_kernel(
    const float* __restrict__ gc,
    const float* __restrict__ gw1, const float* __restrict__ gb1,
    const float* __restrict__ gw2, const float* __restrict__ gb2,
    const float* __restrict__ gw3, const float* __restrict__ gb3,
    float* __restrict__ gout) {
  const int b = blockIdx.x, tid = threadIdx.x;
  __shared__ float xin[1024];
  __shared__ float h1[512];
  __shared__ float h2[256];
#pragma unroll
  for (int i = 0; i < 4; ++i) xin[tid + i * 256] = gc[b * 1024 + tid + i * 256];
  __syncthreads();
  for (int o = tid; o < 512; o += 256) {
    const float* wr = gw1 + (size_t)o * 1024;
    float acc = gb1[o];
    for (int k = 0; k < 1024; k += 4) {
      const float4 wv = *(const float4*)(wr + k);
      acc += wv.x * xin[k] + wv.y * xin[k + 1] + wv.z * xin[k + 2] + wv.w * xin[k + 3];
    }
    h1[o] = gelu_f(acc);
  }
  __syncthreads();
  {
    const float* wr = gw2 + (size_t)tid * 512;
    float acc = gb2[tid];
    for (int k = 0; k < 512; k += 4) {
      const float4 wv = *(const float4*)(wr + k);
      acc += wv.x * h1[k] + wv.y * h1[k + 1] + wv.z * h1[k + 2] + wv.w * h1[k + 3];
    }
    h2[tid] = gelu_f(acc);
  }
  __syncthreads();
  float p = h2[tid] * gw3[tid];
#pragma unroll
  for (int m = 1; m < 64; m <<= 1) p += __shfl_xor(p, m, 64);
  __shared__ float rr[4];
  if ((tid & 63) == 0) rr[tid >> 6] = p;
  __syncthreads();
  if (tid == 0) gout[b] = sigmoid_f(rr[0] + rr[1] + rr[2] + rr[3] + gb3[0]);
}

// ---------------- coupling MLP final layer: (8192,256)@(256,) -> sigmoid ----------------
__global__ __launch_bounds__(256) void gemv_sig_kernel(
    const float* __restrict__ A, const float* __restrict__ w,
    const float* __restrict__ bias, float* __restrict__ out) {
  const int row = blockIdx.x * 4 + (threadIdx.x >> 6);
  const int lane = threadIdx.x & 63;
  F4 a, wv;
  a.v  = ((const float4*)(A + (size_t)row * 256))[lane];
  wv.v = ((const float4*)w)[lane];
  float p = a.f[0] * wv.f[0] + a.f[1] * wv.f[1] + a.f[2] * wv.f[2] + a.f[3] * wv.f[3];
#pragma unroll
  for (int m = 1; m < 64; m <<= 1) p += __shfl_xor(p, m, 64);
  if (lane == 0) out[row] = sigmoid_f(p + bias[0]);
}

// ---------------- mobius coupling update (in place, conjugate pairs) ----------------
__global__ __launch_bounds__(256) void mobius_kernel(
    float* __restrict__ out, const float* __restrict__ tf,
    const float* __restrict__ g, const float* __restrict__ ar,
    const float* __restrict__ res) {
  const int idx = blockIdx.x * 256 + threadIdx.x;   // over 8192*512
  const int row = idx >> 9;
  const int d = idx & 511;
  const int b = row >> 11;
  const float combined = 0.7f * g[b] + 0.3f * tf[row];
  const float coup = 0.1f + ar[0] * (combined - 0.5f) * 2.0f;
  float* base = out + (size_t)row * 1024;
  const float f = base[d], s2 = base[d + 512];
  const float sgn = (d < 256) ? 1.0f : -1.0f;
  float nf = f + sgn * coup * s2;
  float ns = s2 - sgn * coup * f;
  if (res) {
    const float* rb = res + (size_t)row * 1024;
    nf += rb[d];
    ns += rb[d + 512];
  }
  base[d] = nf;
  base[d + 512] = ns;
}

extern "C" void kernel_launch(void* const* d_in, const int* in_sizes, int n_in,
                              void* d_out, int out_size, void* d_ws, size_t ws_size,
                              hipStream_t stream) {
  (void)in_sizes; (void)n_in; (void)out_size; (void)ws_size;
  const float* x    = (const float*)d_in[0];
  const float* g1w  = (const float*)d_in[1];
  const float* g1b  = (const float*)d_in[2];
  const float* g2w  = (const float*)d_in[3];
  const float* g2b  = (const float*)d_in[4];
  const float* Wih0 = (const float*)d_in[5];
  const float* Whh0 = (const float*)d_in[6];
  const float* bih0 = (const float*)d_in[7];
  const float* bhh0 = (const float*)d_in[8];
  const float* Wih1 = (const float*)d_in[9];
  const float* Whh1 = (const float*)d_in[10];
  const float* bih1 = (const float*)d_in[11];
  const float* bhh1 = (const float*)d_in[12];
  const float* cw1 = (const float*)d_in[13]; const float* cb1 = (const float*)d_in[14];
  const float* cw2 = (const float*)d_in[15]; const float* cb2 = (const float*)d_in[16];
  const float* cw3 = (const float*)d_in[17]; const float* cb3 = (const float*)d_in[18];
  const float* cw4 = (const float*)d_in[19]; const float* cb4 = (const float*)d_in[20];
  const float* gw1 = (const float*)d_in[21]; const float* gb1 = (const float*)d_in[22];
  const float* gw2 = (const float*)d_in[23]; const float* gb2 = (const float*)d_in[24];
  const float* gw3 = (const float*)d_in[25]; const float* gb3 = (const float*)d_in[26];
  const float* ar  = (const float*)d_in[27];
  const float* fw1 = (const float*)d_in[28]; const float* fb1 = (const float*)d_in[29];
  const float* fw2 = (const float*)d_in[30]; const float* fb2 = (const float*)d_in[31];
  float* outp = (float*)d_out;

  // workspace layout (floats): A 25165824 | Bb 8388608 | small ~36936
  float* A  = (float*)d_ws;
  float* Bb = A + 25165824;
  float* small = Bb + 8388608;
  float* gc   = small;                 // 4096
  float* gbuf = small + 4096;          // 8
  float* tf   = small + 4104;          // 8192
  float* hb0  = small + 12296;         // 8192 (2x4096 ping-pong, h1)
  float* hb1  = small + 20488;         // 8192 (2x4096 ping-pong, h2)
  unsigned* slots0 = (unsigned*)(small + 28680);  // 2 groups x 128 x 16 u32
  hipMemsetAsync(small, 0, (size_t)(36872 + 64) * sizeof(float), stream);

  // Block 1: LN -> input GEMM (layer-1) -> fused 2-layer pipelined GRU
  ln_kernel<<<8192, 256, 0, stream>>>(x, g1w, g1b, Bb);
  gemm_kernel<<<dim3(24, 64), 256, 0, stream>>>(Bb, 1024, Wih0, 1024, bih0, nullptr,
                                                A, 8192, 3072, 1024, 0);
  gru2_kernel<<<GRU_BLOCKS, 512, 0, stream>>>(A, Whh0, bhh0, Wih1, bih1,
                                              Whh1, bhh1, x, outp,
                                              hb0, hb1, slots0);

  // Block 2: LN -> adaptive mobius (3 cycles) ; x2 lives in outp
  ln_kernel<<<8192, 256, 0, stream>>>(outp, g2w, g2b, Bb);
  colmean_kernel<<<32, 256, 0, stream>>>(Bb, gc);
  gmlp_kernel<<<4, 256, 0, stream>>>(gc, gw1, gb1, gw2, gb2, gw3, gb3, gbuf);
  float* c1o = A;              // 8192x1024
  float* c2o = A + 12582912;   // 8192x512
  float* c3o = A + 20971520;   // 8192x256
  for (int cyc = 0; cyc < 3; ++cyc) {
    gemm_kernel<<<dim3(8, 64), 256, 0, stream>>>(Bb, 1024, cw1, 1024, cb1, nullptr,
                                                 c1o, 8192, 1024, 1024, 1);
    gemm_kernel<<<dim3(4, 64), 256, 0, stream>>>(c1o, 1024, cw2, 1024, cb2, nullptr,
                                                 c2o, 8192, 512, 1024, 1);
    gemm_kernel<<<dim3(2, 64), 256, 0, stream>>>(c2o, 512, cw3, 512, cb3, nullptr,
                                                 c3o, 8192, 256, 512, 1);
    gemv_sig_kernel<<<2048, 256, 0, stream>>>(c3o, cw4, cb4, tf);
    // final cycle fuses x3 = x2 + out
    mobius_kernel<<<16384, 256, 0, stream>>>(Bb, tf, gbuf, ar,
                                             (cyc == 2) ? outp : nullptr);
  }

  // Block 3: FFN residual, K chunked in 2 so hidden fits the A region
  for (int c = 0; c < 2; ++c) {
    gemm_kernel<<<dim3(16, 64), 256, 0, stream>>>(Bb, 1024,
        fw1 + (size_t)c * 2048 * 1024, 1024, fb1 + c * 2048, nullptr,
        A, 8192, 2048, 1024, 1);
    gemm_kernel<<<dim3(8, 64), 256, 0, stream>>>(A, 2048,
        fw2 + c * 2048, 4096, (c == 0) ? fb2 : nullptr,
        (c == 0) ? Bb : outp,
        outp, 8192, 1024, 2048, 0);
  }
}